// Round 7
// baseline (341.458 us; speedup 1.0000x reference)
//
#include <hip/hip_runtime.h>

#define V_N   100000
#define E_N   300000
#define IN_C  256
#define OUT_C 256
#define NREL2 474
#define BN_EPS 1e-5f
#define NB_SCAN 98            // ceil(V_N/1024)
#define MTILES 782            // ceil(V_N/128)

typedef __attribute__((ext_vector_type(8))) short short8;
typedef __attribute__((ext_vector_type(4))) float f32x4;

__device__ __forceinline__ unsigned short f2bf(float f) {
    unsigned int u = __builtin_bit_cast(unsigned int, f);
    u += 0x7FFFu + ((u >> 16) & 1u);          // RNE
    return (unsigned short)(u >> 16);
}
__device__ __forceinline__ unsigned int pk2bf(float lo, float hi) {
    return (unsigned int)f2bf(lo) | ((unsigned int)f2bf(hi) << 16);
}

typedef const __attribute__((address_space(1))) unsigned int* gas1_t;
typedef __attribute__((address_space(3))) unsigned int* las3_t;
__device__ __forceinline__ void gload16(const void* g, void* l) {
    __builtin_amdgcn_global_load_lds((gas1_t)g, (las3_t)l, 16, 0, 0);
}

// ---------------- CSR build ----------------

__global__ void count_kernel(const int* __restrict__ dst, int* __restrict__ cnt) {
    int e = blockIdx.x * 256 + threadIdx.x;
    if (e < E_N) atomicAdd(&cnt[dst[e]], 1);
}

// coalesced per-block sums; also emits degi = rsqrt(cnt)
__global__ __launch_bounds__(1024)
void scan1(const int* __restrict__ cnt, int* __restrict__ bsum, float* __restrict__ degi) {
    __shared__ int red[1024];
    int t = threadIdx.x;
    int v = blockIdx.x * 1024 + t;
    int c = (v < V_N) ? cnt[v] : 0;
    if (v < V_N) degi[v] = c > 0 ? rsqrtf((float)c) : 0.f;
    red[t] = c;
    __syncthreads();
    for (int s = 512; s > 0; s >>= 1) {
        if (t < s) red[t] += red[t + s];
        __syncthreads();
    }
    if (t == 0) bsum[blockIdx.x] = red[0];
}

// parallel exclusive scan of the 98 block sums (one 128-thread block)
__global__ void scan2(int* bsum) {
    __shared__ int sc[128];
    int t = threadIdx.x;
    int v = (t < NB_SCAN) ? bsum[t] : 0;
    sc[t] = v;
    __syncthreads();
    for (int d = 1; d < 128; d <<= 1) {
        int add = (t >= d) ? sc[t - d] : 0;
        __syncthreads();
        sc[t] += add;
        __syncthreads();
    }
    if (t < NB_SCAN) bsum[t] = sc[t] - v;   // exclusive
}

__global__ __launch_bounds__(1024)
void scan3(const int* __restrict__ cnt, const int* __restrict__ bsum,
           int* __restrict__ offs) {
    __shared__ int sc[1024];
    int t = threadIdx.x;
    int v = blockIdx.x * 1024 + t;
    int c = (v < V_N) ? cnt[v] : 0;
    sc[t] = c;
    __syncthreads();
    for (int d = 1; d < 1024; d <<= 1) {
        int add = (t >= d) ? sc[t - d] : 0;
        __syncthreads();
        sc[t] += add;
        __syncthreads();
    }
    if (v < V_N) offs[v] = sc[t] - c + bsum[blockIdx.x];
}

__global__ void scatter_kernel(const int* __restrict__ dst, const int* __restrict__ src,
                               const int* __restrict__ etype, const int* __restrict__ edir,
                               const int* __restrict__ offs, int* __restrict__ cursor,
                               int* __restrict__ epack) {
    int e = blockIdx.x * 256 + threadIdx.x;
    if (e < E_N) {
        int d = dst[e];
        int pos = offs[d] + atomicAdd(&cursor[d], 1);
        epack[pos] = src[e] | (etype[e] << 17) | (edir[e] << 26);
    }
}

// WcT[n][k] = bf16(w_flat[k][n]); rows k>=512 pre-multiplied by loop_rel[k-512]
__global__ void convert_w(const float* __restrict__ w, const float* __restrict__ loop_rel,
                          unsigned short* __restrict__ WcT) {
    int k = blockIdx.x;    // 0..767
    int n = threadIdx.x;   // 0..255
    float f = w[(size_t)k * 256 + n];
    if (k >= 512) f *= loop_rel[k - 512];
    WcT[(size_t)n * 768 + k] = f2bf(f);
}

// ---------------- aggregate: HALF-WAVE (32 lanes) per dst node ----------------
// Apre[v][0..255]=dir0 agg, [256..511]=dir1 agg (bf16).
// Also emits xbf = bf16(x[v]) tile-locally: outu + (v>>7)*65536 + (v&127)*256 + c.
__global__ __launch_bounds__(256)
void aggregate(const float* __restrict__ x, const float* __restrict__ rel_repr,
               const float* __restrict__ degi,
               const int* __restrict__ cnt, const int* __restrict__ offs,
               const int* __restrict__ epack, unsigned short* __restrict__ Apre,
               unsigned short* __restrict__ outu) {
    const int node = (blockIdx.x * 256 + threadIdx.x) >> 5;
    const int lane = threadIdx.x & 31;
    if (node >= V_N) return;
    const int v = node;
    const int n = cnt[v];
    const int base = offs[v];
    const float dv = degi[v];
    const int c8 = lane * 8;                 // this lane owns 8 floats of the row

    float4 a0l = {0,0,0,0}, a0h = {0,0,0,0};
    float4 a1l = {0,0,0,0}, a1h = {0,0,0,0};

    int i = 0;
    for (; i + 2 <= n; i += 2) {
        int p0 = epack[base + i];
        int p1 = epack[base + i + 1];
        int s0 = p0 & 0x1FFFF, s1 = p1 & 0x1FFFF;
        int t0 = (p0 >> 17) & 0x1FF, t1 = (p1 >> 17) & 0x1FF;
        float en0 = degi[s0] * dv, en1 = degi[s1] * dv;
        float e00 = (p0 & (1 << 26)) ? 0.f : en0, e01 = en0 - e00;
        float e10 = (p1 & (1 << 26)) ? 0.f : en1, e11 = en1 - e10;
        const float* xr0 = x + (size_t)s0 * IN_C + c8;
        const float* rr0 = rel_repr + (size_t)t0 * IN_C + c8;
        const float* xr1 = x + (size_t)s1 * IN_C + c8;
        const float* rr1 = rel_repr + (size_t)t1 * IN_C + c8;
        float4 xa0 = *(const float4*)xr0, xb0 = *(const float4*)(xr0 + 4);
        float4 ra0 = *(const float4*)rr0, rb0 = *(const float4*)(rr0 + 4);
        float4 xa1 = *(const float4*)xr1, xb1 = *(const float4*)(xr1 + 4);
        float4 ra1 = *(const float4*)rr1, rb1 = *(const float4*)(rr1 + 4);
        float4 ma, mb;
        ma.x = xa0.x * ra0.x; ma.y = xa0.y * ra0.y; ma.z = xa0.z * ra0.z; ma.w = xa0.w * ra0.w;
        mb.x = xb0.x * rb0.x; mb.y = xb0.y * rb0.y; mb.z = xb0.z * rb0.z; mb.w = xb0.w * rb0.w;
        a0l.x += ma.x * e00; a0l.y += ma.y * e00; a0l.z += ma.z * e00; a0l.w += ma.w * e00;
        a0h.x += mb.x * e00; a0h.y += mb.y * e00; a0h.z += mb.z * e00; a0h.w += mb.w * e00;
        a1l.x += ma.x * e01; a1l.y += ma.y * e01; a1l.z += ma.z * e01; a1l.w += ma.w * e01;
        a1h.x += mb.x * e01; a1h.y += mb.y * e01; a1h.z += mb.z * e01; a1h.w += mb.w * e01;
        ma.x = xa1.x * ra1.x; ma.y = xa1.y * ra1.y; ma.z = xa1.z * ra1.z; ma.w = xa1.w * ra1.w;
        mb.x = xb1.x * rb1.x; mb.y = xb1.y * rb1.y; mb.z = xb1.z * rb1.z; mb.w = xb1.w * rb1.w;
        a0l.x += ma.x * e10; a0l.y += ma.y * e10; a0l.z += ma.z * e10; a0l.w += ma.w * e10;
        a0h.x += mb.x * e10; a0h.y += mb.y * e10; a0h.z += mb.z * e10; a0h.w += mb.w * e10;
        a1l.x += ma.x * e11; a1l.y += ma.y * e11; a1l.z += ma.z * e11; a1l.w += ma.w * e11;
        a1h.x += mb.x * e11; a1h.y += mb.y * e11; a1h.z += mb.z * e11; a1h.w += mb.w * e11;
    }
    if (i < n) {
        int p = epack[base + i];
        int s = p & 0x1FFFF;
        int tt = (p >> 17) & 0x1FF;
        float en = degi[s] * dv;
        float e0 = (p & (1 << 26)) ? 0.f : en, e1 = en - e0;
        const float* xr = x + (size_t)s * IN_C + c8;
        const float* rr = rel_repr + (size_t)tt * IN_C + c8;
        float4 xa = *(const float4*)xr, xb = *(const float4*)(xr + 4);
        float4 ra = *(const float4*)rr, rb = *(const float4*)(rr + 4);
        float4 ma, mb;
        ma.x = xa.x * ra.x; ma.y = xa.y * ra.y; ma.z = xa.z * ra.z; ma.w = xa.w * ra.w;
        mb.x = xb.x * rb.x; mb.y = xb.y * rb.y; mb.z = xb.z * rb.z; mb.w = xb.w * rb.w;
        a0l.x += ma.x * e0; a0l.y += ma.y * e0; a0l.z += ma.z * e0; a0l.w += ma.w * e0;
        a0h.x += mb.x * e0; a0h.y += mb.y * e0; a0h.z += mb.z * e0; a0h.w += mb.w * e0;
        a1l.x += ma.x * e1; a1l.y += ma.y * e1; a1l.z += ma.z * e1; a1l.w += ma.w * e1;
        a1h.x += mb.x * e1; a1h.y += mb.y * e1; a1h.z += mb.z * e1; a1h.w += mb.w * e1;
    }

    uint4 u0, u1;
    u0.x = pk2bf(a0l.x, a0l.y); u0.y = pk2bf(a0l.z, a0l.w);
    u0.z = pk2bf(a0h.x, a0h.y); u0.w = pk2bf(a0h.z, a0h.w);
    u1.x = pk2bf(a1l.x, a1l.y); u1.y = pk2bf(a1l.z, a1l.w);
    u1.z = pk2bf(a1h.x, a1h.y); u1.w = pk2bf(a1h.z, a1h.w);
    *(uint4*)(Apre + (size_t)v * 512 + c8)       = u0;
    *(uint4*)(Apre + (size_t)v * 512 + 256 + c8) = u1;

    // xbf (self-loop A operand; loop_rel folded into WcT)
    const float* xv = x + (size_t)v * IN_C + c8;
    float4 xl = *(const float4*)xv, xh = *(const float4*)(xv + 4);
    uint4 ux;
    ux.x = pk2bf(xl.x, xl.y); ux.y = pk2bf(xl.z, xl.w);
    ux.z = pk2bf(xh.x, xh.y); ux.w = pk2bf(xh.z, xh.w);
    *(uint4*)(outu + (size_t)(v >> 7) * 65536 + (size_t)(v & 127) * 256 + c8) = ux;
}

// ---------------- fused GEMM, 2-deep counted-vmcnt pipeline, BK=32, 48KB LDS ----------------
// out_h(bf16, into Apre rows) = [Apre | xbf] @ WcT^T, /3 + bias; BN col partials.
// 128 rows x 256 cols per block, 8 waves (2x4). K=768, BK=32, 24 steps.
// LDS chunk layout is column-major (L = kc*ROWS + row): fragment reads are
// 16 consecutive 16B chunks per lane-group = 2-way bank alias = free; the
// global_load_lds source mapping is linear (no swizzle needed).
// A dbuf 2x8KB @0, B dbuf 2x16KB @16384 (48KB total -> 3 blocks/CU).
__global__ __launch_bounds__(512, 4)
void mfma_gemm(unsigned short* Ap /* Apre, also h output */,
               const unsigned short* __restrict__ xbf,
               const unsigned short* __restrict__ WcT,
               const float* __restrict__ bias, float* __restrict__ partial) {
    __shared__ __align__(16) unsigned char smem[49152];

    const int t    = threadIdx.x;
    const int m0   = blockIdx.x * 128;
    const int wid  = t >> 6;
    const int lane = t & 63;
    const int wm   = wid >> 2;
    const int wn   = wid & 3;
    const int lr   = lane & 15;
    const int qk   = lane >> 4;
    const int wbase = t & 0x1C0;

    // A staging: thread t fills chunk L=t: row = t&127, k-chunk = t>>7
    const int ar  = t & 127;
    const int akc = t >> 7;
    int rg = m0 + ar; if (rg >= V_N) rg = V_N - 1;

    auto A_lds = [&](int buf) { return (unsigned short*)(smem + buf * 8192); };
    auto B_lds = [&](int buf) { return (unsigned short*)(smem + 16384 + buf * 16384); };

    auto stage = [&](int buf, int ks) {
        // A: 1 chunk/thread (3 VMEM total per thread per stage -> vmcnt(3))
        const unsigned short* sa = (ks < 16)
            ? Ap  + (size_t)rg * 512 + ks * 32 + akc * 8
            : xbf + (size_t)blockIdx.x * 65536 + (size_t)ar * 256 + (ks - 16) * 32 + akc * 8;
        gload16(sa, A_lds(buf) + (size_t)wbase * 8);
        // B: 2 chunks/thread; chunk L = j*512+t: n = L&255, k-chunk = L>>8
        #pragma unroll
        for (int j = 0; j < 2; ++j) {
            int L = j * 512 + t;
            int n = L & 255, kc = L >> 8;
            const unsigned short* sb = WcT + (size_t)n * 768 + ks * 32 + kc * 8;
            gload16(sb, B_lds(buf) + (size_t)(j * 512 + wbase) * 8);
        }
    };

    f32x4 acc[4][4];
    #pragma unroll
    for (int m = 0; m < 4; m++)
        #pragma unroll
        for (int n = 0; n < 4; n++)
            acc[m][n] = (f32x4){0.f, 0.f, 0.f, 0.f};

    stage(0, 0);
    stage(1, 1);

    #pragma unroll
    for (int ks = 0; ks < 24; ++ks) {
        const int buf = ks & 1;
        if (ks < 23) { asm volatile("s_waitcnt vmcnt(3)" ::: "memory"); }
        else         { asm volatile("s_waitcnt vmcnt(0)" ::: "memory"); }
        __builtin_amdgcn_s_barrier();
        __builtin_amdgcn_sched_barrier(0);
        const unsigned short* Ab = A_lds(buf);
        const unsigned short* Bb = B_lds(buf);
        short8 av[4], bv[4];
        #pragma unroll
        for (int m = 0; m < 4; m++)
            av[m] = *(const short8*)&Ab[(size_t)(qk * 128 + wm * 64 + m * 16 + lr) * 8];
        #pragma unroll
        for (int n = 0; n < 4; n++)
            bv[n] = *(const short8*)&Bb[(size_t)(qk * 256 + wn * 64 + n * 16 + lr) * 8];
        #pragma unroll
        for (int m = 0; m < 4; m++)
            #pragma unroll
            for (int n = 0; n < 4; n++)
                acc[m][n] = __builtin_amdgcn_mfma_f32_16x16x32_bf16(av[m], bv[n], acc[m][n], 0, 0, 0);
        __builtin_amdgcn_sched_barrier(0);
        __builtin_amdgcn_s_barrier();
        __builtin_amdgcn_sched_barrier(0);
        if (ks + 2 < 24) stage(buf, ks + 2);
    }

    // ---- epilogue: h = acc/3 + bias (bf16), LDS-staged coalesced store, BN partials ----
    unsigned short* Cst = (unsigned short*)smem;     // [64][264] ushort = 33792 B
    float* bs = (float*)(smem + 34816);              // 512 floats
    bs[t] = 0.f;
    __syncthreads();

    const float inv3 = 1.f / 3.f;
    float bco[4];
    #pragma unroll
    for (int n = 0; n < 4; n++) bco[n] = bias[wn * 64 + n * 16 + lr];

    float s[4]  = {0.f, 0.f, 0.f, 0.f};
    float s2[4] = {0.f, 0.f, 0.f, 0.f};

    #pragma unroll
    for (int p = 0; p < 2; ++p) {
        if (wm == p) {
            #pragma unroll
            for (int m = 0; m < 4; m++) {
                #pragma unroll
                for (int n = 0; n < 4; n++) {
                    const int col = wn * 64 + n * 16 + lr;
                    #pragma unroll
                    for (int j = 0; j < 4; j++) {
                        int rl = m * 16 + qk * 4 + j;
                        float h = acc[m][n][j] * inv3 + bco[n];
                        if (m0 + p * 64 + rl < V_N) { s[n] += h; s2[n] += h * h; }
                        Cst[rl * 264 + col] = f2bf(h);
                    }
                }
            }
        }
        __syncthreads();
        #pragma unroll
        for (int i = 0; i < 4; ++i) {
            int f = t + i * 512;            // 0..2047 chunks of 8 ushorts
            int row = f >> 5;
            int c8  = (f & 31) * 8;
            int r = m0 + p * 64 + row;
            if (r < V_N) {
                uint4 val = *(const uint4*)&Cst[row * 264 + c8];
                *(uint4*)&Ap[(size_t)r * 512 + c8] = val;
            }
        }
        __syncthreads();
    }

    #pragma unroll
    for (int n = 0; n < 4; n++) {
        s[n]  += __shfl_xor(s[n], 16);  s[n]  += __shfl_xor(s[n], 32);
        s2[n] += __shfl_xor(s2[n], 16); s2[n] += __shfl_xor(s2[n], 32);
    }
    if (lane < 16) {
        #pragma unroll
        for (int n = 0; n < 4; n++) {
            const int col = wn * 64 + n * 16 + lr;
            atomicAdd(&bs[col], s[n]);
            atomicAdd(&bs[256 + col], s2[n]);
        }
    }
    __syncthreads();
    partial[(size_t)blockIdx.x * 512 + t] = bs[t];
}

// ---------------- BN reduce + finalize + normalize ----------------

__global__ void bn_reduce_part(const float* __restrict__ partial, float* __restrict__ sums) {
    int t = threadIdx.x;                       // 512
    int b0 = blockIdx.x * 196;
    int b1 = b0 + 196; if (b1 > MTILES) b1 = MTILES;
    float S = 0.f;
    for (int b = b0; b < b1; b++) S += partial[(size_t)b * 512 + t];
    atomicAdd(&sums[t], S);
}

__global__ void bn_finalize(const float* __restrict__ sums, float* __restrict__ ms) {
    int c = threadIdx.x;                       // 256
    float mean = sums[c] / (float)V_N;
    float var  = sums[256 + c] / (float)V_N - mean * mean;
    ms[c]       = mean;
    ms[256 + c] = rsqrtf(var + BN_EPS);
}

// read h (bf16, Apre rows), write normalized f32 out
__global__ void bn_norm2(const unsigned short* __restrict__ hbf,
                         const float* __restrict__ ms, float* __restrict__ out) {
    const size_t total8 = (size_t)V_N * 32;    // chunks of 8 elems
    size_t stride = (size_t)gridDim.x * blockDim.x;
    for (size_t idx = (size_t)blockIdx.x * blockDim.x + threadIdx.x; idx < total8; idx += stride) {
        size_t v  = idx >> 5;
        int   c8  = (int)(idx & 31) * 8;
        uint4 uv = *(const uint4*)&hbf[v * 512 + c8];
        float4 ma = *(const float4*)&ms[c8];
        float4 mb = *(const float4*)&ms[c8 + 4];
        float4 ra = *(const float4*)&ms[256 + c8];
        float4 rb = *(const float4*)&ms[256 + c8 + 4];
        unsigned int w0 = uv.x, w1 = uv.y, w2 = uv.z, w3 = uv.w;
        float4 h0, h1;
        h0.x = (__builtin_bit_cast(float, (w0 << 16))        - ma.x) * ra.x;
        h0.y = (__builtin_bit_cast(float, (w0 & 0xFFFF0000u)) - ma.y) * ra.y;
        h0.z = (__builtin_bit_cast(float, (w1 << 16))        - ma.z) * ra.z;
        h0.w = (__builtin_bit_cast(float, (w1 & 0xFFFF0000u)) - ma.w) * ra.w;
        h1.x = (__builtin_bit_cast(float, (w2 << 16))        - mb.x) * rb.x;
        h1.y = (__builtin_bit_cast(float, (w2 & 0xFFFF0000u)) - mb.y) * rb.y;
        h1.z = (__builtin_bit_cast(float, (w3 << 16))        - mb.z) * rb.z;
        h1.w = (__builtin_bit_cast(float, (w3 & 0xFFFF0000u)) - mb.w) * rb.w;
        float* o = out + v * 256 + c8;
        *(float4*)o       = h0;
        *(float4*)(o + 4) = h1;
    }
}

__global__ void rel_out_kernel(const float* __restrict__ rel_repr,
                               const float* __restrict__ loop_rel,
                               const float* __restrict__ w_rel,
                               float* __restrict__ out)
{
    int r = blockIdx.x;
    const float* row = (r < NREL2) ? (rel_repr + (size_t)r * IN_C) : loop_rel;
    int l = threadIdx.x;
    float s = 0.f;
    #pragma unroll
    for (int q = 0; q < 4; q++) {
        int k = l + q * 64;
        s += row[k] * w_rel[(size_t)k * OUT_C + (OUT_C - 1)];
    }
    #pragma unroll
    for (int m = 32; m >= 1; m >>= 1) s += __shfl_xor(s, m);
    if (l == 0) out[(size_t)V_N * OUT_C + r] = s;
}

// ---------------- launch ----------------

extern "C" void kernel_launch(void* const* d_in, const int* in_sizes, int n_in,
                              void* d_out, int out_size, void* d_ws, size_t ws_size,
                              hipStream_t stream) {
    const float* x        = (const float*)d_in[0];
    const float* rel_repr = (const float*)d_in[1];
    const float* w        = (const float*)d_in[2];
    const float* w_rel    = (const float*)d_in[3];
    const float* loop_rel = (const float*)d_in[4];
    const float* bias     = (const float*)d_in[5];
    const int*   src      = (const int*)d_in[6];
    const int*   dst      = (const int*)d_in[7];
    const int*   etype    = (const int*)d_in[8];
    const int*   edir     = (const int*)d_in[9];
    float* out = (float*)d_out;
    unsigned short* outu = (unsigned short*)d_out;

    // workspace layout (105.60 MB, within round-2-proven bound)
    char* wsb = (char*)d_ws;
    int*   cnt     = (int*)(wsb + 0);              // 400,000
    int*   cursor  = (int*)(wsb + 400000);         // 400,000
    int*   offs    = (int*)(wsb + 800000);         // 400,000
    float* degi    = (float*)(wsb + 1200000);      // 400,000
    int*   bsum    = (int*)(wsb + 1600000);        // 392
    float* partial = (float*)(wsb + 0);            // alias region0 (1,601,536 < 1,601,792)
    int*   epack   = (int*)(wsb + 1601792);        // 1,200,000
    float* ms      = (float*)(wsb + 2801792);      // 2048
    float* sums    = (float*)(wsb + 2803840);      // 2048
    unsigned short* WcT  = (unsigned short*)(wsb + 2805888);   // 393,216
    unsigned short* Apre = (unsigned short*)(wsb + 3199104);   // 102,400,000

    hipMemsetAsync(wsb, 0, 800000, stream);        // cnt + cursor
    hipMemsetAsync(sums, 0, 2048, stream);

    count_kernel<<<(E_N + 255) / 256, 256, 0, stream>>>(dst, cnt);
    scan1<<<NB_SCAN, 1024, 0, stream>>>(cnt, bsum, degi);
    scan2<<<1, 128, 0, stream>>>(bsum);
    scan3<<<NB_SCAN, 1024, 0, stream>>>(cnt, bsum, offs);
    scatter_kernel<<<(E_N + 255) / 256, 256, 0, stream>>>(dst, src, etype, edir,
                                                          offs, cursor, epack);
    convert_w<<<768, 256, 0, stream>>>(w, loop_rel, WcT);
    aggregate<<<(V_N * 32 + 255) / 256, 256, 0, stream>>>(x, rel_repr, degi, cnt, offs,
                                                          epack, Apre, outu);
    mfma_gemm<<<MTILES, 512, 0, stream>>>(Apre, outu, WcT, bias, partial);
    bn_reduce_part<<<4, 512, 0, stream>>>(partial, sums);
    bn_finalize<<<1, 256, 0, stream>>>(sums, ms);
    bn_norm2<<<2048, 256, 0, stream>>>(Apre, ms, out);
    rel_out_kernel<<<NREL2 + 1, 64, 0, stream>>>(rel_repr, loop_rel, w_rel, out);
}

// Round 8
// 275.875 us; speedup vs baseline: 1.2377x; 1.2377x over previous
//
#include <hip/hip_runtime.h>

#define V_N   100000
#define E_N   300000
#define IN_C  256
#define OUT_C 256
#define NREL2 474
#define BN_EPS 1e-5f
#define NB_SCAN 98            // ceil(V_N/1024)
#define MTILES 782            // ceil(V_N/128)

typedef __attribute__((ext_vector_type(8))) short short8;
typedef __attribute__((ext_vector_type(4))) float f32x4;

__device__ __forceinline__ unsigned short f2bf(float f) {
    unsigned int u = __builtin_bit_cast(unsigned int, f);
    u += 0x7FFFu + ((u >> 16) & 1u);          // RNE
    return (unsigned short)(u >> 16);
}
__device__ __forceinline__ unsigned int pk2bf(float lo, float hi) {
    return (unsigned int)f2bf(lo) | ((unsigned int)f2bf(hi) << 16);
}
__device__ __forceinline__ float blo(unsigned int u) {
    return __builtin_bit_cast(float, u << 16);
}
__device__ __forceinline__ float bhi(unsigned int u) {
    return __builtin_bit_cast(float, u & 0xFFFF0000u);
}

typedef const __attribute__((address_space(1))) unsigned int* gas1_t;
typedef __attribute__((address_space(3))) unsigned int* las3_t;
__device__ __forceinline__ void gload16(const void* g, void* l) {
    __builtin_amdgcn_global_load_lds((gas1_t)g, (las3_t)l, 16, 0, 0);
}

// ---------------- CSR build ----------------

__global__ void count_kernel(const int* __restrict__ dst, int* __restrict__ cnt) {
    int e = blockIdx.x * 256 + threadIdx.x;
    if (e < E_N) atomicAdd(&cnt[dst[e]], 1);
}

// coalesced per-block sums; also emits degi = rsqrt(cnt)
__global__ __launch_bounds__(1024)
void scan1(const int* __restrict__ cnt, int* __restrict__ bsum, float* __restrict__ degi) {
    __shared__ int red[1024];
    int t = threadIdx.x;
    int v = blockIdx.x * 1024 + t;
    int c = (v < V_N) ? cnt[v] : 0;
    if (v < V_N) degi[v] = c > 0 ? rsqrtf((float)c) : 0.f;
    red[t] = c;
    __syncthreads();
    for (int s = 512; s > 0; s >>= 1) {
        if (t < s) red[t] += red[t + s];
        __syncthreads();
    }
    if (t == 0) bsum[blockIdx.x] = red[0];
}

// parallel exclusive scan of the 98 block sums (one 128-thread block)
__global__ void scan2(int* bsum) {
    __shared__ int sc[128];
    int t = threadIdx.x;
    int v = (t < NB_SCAN) ? bsum[t] : 0;
    sc[t] = v;
    __syncthreads();
    for (int d = 1; d < 128; d <<= 1) {
        int add = (t >= d) ? sc[t - d] : 0;
        __syncthreads();
        sc[t] += add;
        __syncthreads();
    }
    if (t < NB_SCAN) bsum[t] = sc[t] - v;   // exclusive
}

__global__ __launch_bounds__(1024)
void scan3(const int* __restrict__ cnt, const int* __restrict__ bsum,
           int* __restrict__ offs) {
    __shared__ int sc[1024];
    int t = threadIdx.x;
    int v = blockIdx.x * 1024 + t;
    int c = (v < V_N) ? cnt[v] : 0;
    sc[t] = c;
    __syncthreads();
    for (int d = 1; d < 1024; d <<= 1) {
        int add = (t >= d) ? sc[t - d] : 0;
        __syncthreads();
        sc[t] += add;
        __syncthreads();
    }
    if (v < V_N) offs[v] = sc[t] - c + bsum[blockIdx.x];
}

__global__ void scatter_kernel(const int* __restrict__ dst, const int* __restrict__ src,
                               const int* __restrict__ etype, const int* __restrict__ edir,
                               const int* __restrict__ offs, int* __restrict__ cursor,
                               int* __restrict__ epack) {
    int e = blockIdx.x * 256 + threadIdx.x;
    if (e < E_N) {
        int d = dst[e];
        int pos = offs[d] + atomicAdd(&cursor[d], 1);
        epack[pos] = src[e] | (etype[e] << 17) | (edir[e] << 26);
    }
}

// WcT[n][k] = bf16(w_flat[k][n]); rows k>=512 pre-multiplied by loop_rel[k-512]
__global__ void convert_w(const float* __restrict__ w, const float* __restrict__ loop_rel,
                          unsigned short* __restrict__ WcT) {
    int k = blockIdx.x;    // 0..767
    int n = threadIdx.x;   // 0..255
    float f = w[(size_t)k * 256 + n];
    if (k >= 512) f *= loop_rel[k - 512];
    WcT[(size_t)n * 768 + k] = f2bf(f);
}

// x -> xbf (bf16, plain [V][256], lives in d_out scratch)
__global__ void convert_x(const float* __restrict__ x, unsigned short* __restrict__ xbf) {
    const size_t total8 = (size_t)V_N * 32;    // 8-elem chunks
    size_t stride = (size_t)gridDim.x * blockDim.x;
    for (size_t idx = (size_t)blockIdx.x * blockDim.x + threadIdx.x; idx < total8; idx += stride) {
        const float* s = x + idx * 8;
        float4 a = *(const float4*)s, b = *(const float4*)(s + 4);
        uint4 u;
        u.x = pk2bf(a.x, a.y); u.y = pk2bf(a.z, a.w);
        u.z = pk2bf(b.x, b.y); u.w = pk2bf(b.z, b.w);
        *(uint4*)(xbf + idx * 8) = u;
    }
}

// rel_repr -> relbf (bf16, [NREL2][256])
__global__ void convert_rel(const float* __restrict__ rel, unsigned short* __restrict__ relbf) {
    const int total8 = NREL2 * 32;
    int idx = blockIdx.x * 256 + threadIdx.x;
    if (idx < total8) {
        const float* s = rel + (size_t)idx * 8;
        float4 a = *(const float4*)s, b = *(const float4*)(s + 4);
        uint4 u;
        u.x = pk2bf(a.x, a.y); u.y = pk2bf(a.z, a.w);
        u.z = pk2bf(b.x, b.y); u.w = pk2bf(b.z, b.w);
        *(uint4*)(relbf + (size_t)idx * 8) = u;
    }
}

// ---------------- aggregate: HALF-WAVE (32 lanes) per dst node, bf16 gathers ----------------
// Apre[v][0..255]=dir0 agg, [256..511]=dir1 agg (bf16).
__global__ __launch_bounds__(256)
void aggregate(const unsigned short* __restrict__ xbf,
               const unsigned short* __restrict__ relbf,
               const float* __restrict__ degi,
               const int* __restrict__ cnt, const int* __restrict__ offs,
               const int* __restrict__ epack, unsigned short* __restrict__ Apre) {
    const int node = (blockIdx.x * 256 + threadIdx.x) >> 5;
    const int lane = threadIdx.x & 31;
    if (node >= V_N) return;
    const int v = node;
    const int n = cnt[v];
    const int base = offs[v];
    const float dv = degi[v];
    const int c8 = lane * 8;                 // this lane owns 8 elems of the row

    float a0[8] = {0,0,0,0,0,0,0,0};
    float a1[8] = {0,0,0,0,0,0,0,0};

    int i = 0;
    for (; i + 2 <= n; i += 2) {
        int p0 = epack[base + i];
        int p1 = epack[base + i + 1];
        int s0 = p0 & 0x1FFFF, s1 = p1 & 0x1FFFF;
        int t0 = (p0 >> 17) & 0x1FF, t1 = (p1 >> 17) & 0x1FF;
        float en0 = degi[s0] * dv, en1 = degi[s1] * dv;
        float e00 = (p0 & (1 << 26)) ? 0.f : en0, e01 = en0 - e00;
        float e10 = (p1 & (1 << 26)) ? 0.f : en1, e11 = en1 - e10;
        uint4 xu0 = *(const uint4*)(xbf   + (size_t)s0 * 256 + c8);
        uint4 ru0 = *(const uint4*)(relbf + (size_t)t0 * 256 + c8);
        uint4 xu1 = *(const uint4*)(xbf   + (size_t)s1 * 256 + c8);
        uint4 ru1 = *(const uint4*)(relbf + (size_t)t1 * 256 + c8);
        float m[8];
        m[0] = blo(xu0.x) * blo(ru0.x); m[1] = bhi(xu0.x) * bhi(ru0.x);
        m[2] = blo(xu0.y) * blo(ru0.y); m[3] = bhi(xu0.y) * bhi(ru0.y);
        m[4] = blo(xu0.z) * blo(ru0.z); m[5] = bhi(xu0.z) * bhi(ru0.z);
        m[6] = blo(xu0.w) * blo(ru0.w); m[7] = bhi(xu0.w) * bhi(ru0.w);
        #pragma unroll
        for (int j = 0; j < 8; j++) { a0[j] += m[j] * e00; a1[j] += m[j] * e01; }
        m[0] = blo(xu1.x) * blo(ru1.x); m[1] = bhi(xu1.x) * bhi(ru1.x);
        m[2] = blo(xu1.y) * blo(ru1.y); m[3] = bhi(xu1.y) * bhi(ru1.y);
        m[4] = blo(xu1.z) * blo(ru1.z); m[5] = bhi(xu1.z) * bhi(ru1.z);
        m[6] = blo(xu1.w) * blo(ru1.w); m[7] = bhi(xu1.w) * bhi(ru1.w);
        #pragma unroll
        for (int j = 0; j < 8; j++) { a0[j] += m[j] * e10; a1[j] += m[j] * e11; }
    }
    if (i < n) {
        int p = epack[base + i];
        int s = p & 0x1FFFF;
        int tt = (p >> 17) & 0x1FF;
        float en = degi[s] * dv;
        float e0 = (p & (1 << 26)) ? 0.f : en, e1 = en - e0;
        uint4 xu = *(const uint4*)(xbf   + (size_t)s * 256 + c8);
        uint4 ru = *(const uint4*)(relbf + (size_t)tt * 256 + c8);
        float m[8];
        m[0] = blo(xu.x) * blo(ru.x); m[1] = bhi(xu.x) * bhi(ru.x);
        m[2] = blo(xu.y) * blo(ru.y); m[3] = bhi(xu.y) * bhi(ru.y);
        m[4] = blo(xu.z) * blo(ru.z); m[5] = bhi(xu.z) * bhi(ru.z);
        m[6] = blo(xu.w) * blo(ru.w); m[7] = bhi(xu.w) * bhi(ru.w);
        #pragma unroll
        for (int j = 0; j < 8; j++) { a0[j] += m[j] * e0; a1[j] += m[j] * e1; }
    }

    uint4 u0, u1;
    u0.x = pk2bf(a0[0], a0[1]); u0.y = pk2bf(a0[2], a0[3]);
    u0.z = pk2bf(a0[4], a0[5]); u0.w = pk2bf(a0[6], a0[7]);
    u1.x = pk2bf(a1[0], a1[1]); u1.y = pk2bf(a1[2], a1[3]);
    u1.z = pk2bf(a1[4], a1[5]); u1.w = pk2bf(a1[6], a1[7]);
    *(uint4*)(Apre + (size_t)v * 512 + c8)       = u0;
    *(uint4*)(Apre + (size_t)v * 512 + 256 + c8) = u1;
}

// ---------------- fused GEMM, 2-deep counted-vmcnt pipeline (round-5 proven) ----------------
// out_h(bf16, into Apre rows) = [Apre | xbf] @ WcT^T, /3 + bias; BN col partials.
// 128 rows x 256 cols per block, 8 waves (2x4). K=768, BK=64, 12 steps.
// LDS: A dbuf 2x16KB @0, B dbuf 2x32KB @32768 (96KB). Epilogue reuses LDS.
__global__ __launch_bounds__(512)
void mfma_gemm(unsigned short* Ap /* Apre, also h output */,
               const unsigned short* __restrict__ xbf,
               const unsigned short* __restrict__ WcT,
               const float* __restrict__ bias, float* __restrict__ partial) {
    __shared__ __align__(16) unsigned char smem[98304];

    const int t    = threadIdx.x;
    const int m0   = blockIdx.x * 128;
    const int wid  = t >> 6;
    const int lane = t & 63;
    const int wm   = wid >> 2;
    const int wn   = wid & 3;
    const int lr   = lane & 15;
    const int qk   = lane >> 4;
    const int sxr  = lr & 7;
    const int wbase = t & 0x1C0;

    // staging constants
    int arow[2], acsw[2], brow[4], bcsw[4];
    #pragma unroll
    for (int j = 0; j < 2; ++j) {
        int g = j * 512 + t;
        arow[j] = g >> 3;
        acsw[j] = (g & 7) ^ (arow[j] & 7);
    }
    #pragma unroll
    for (int j = 0; j < 4; ++j) {
        int g = j * 512 + t;
        brow[j] = g >> 3;
        bcsw[j] = (g & 7) ^ (brow[j] & 7);
    }

    auto A_lds = [&](int buf) { return (unsigned short*)(smem + buf * 16384); };
    auto B_lds = [&](int buf) { return (unsigned short*)(smem + 32768 + buf * 32768); };

    auto stage = [&](int buf, int ks) {
        #pragma unroll
        for (int j = 0; j < 2; ++j) {
            int rg = m0 + arow[j];
            if (rg >= V_N) rg = V_N - 1;
            const unsigned short* s = (ks < 8)
                ? Ap  + (size_t)rg * 512 + ks * 64 + acsw[j] * 8
                : xbf + (size_t)rg * 256 + (ks - 8) * 64 + acsw[j] * 8;
            gload16(s, A_lds(buf) + (size_t)(j * 512 + wbase) * 8);
        }
        #pragma unroll
        for (int j = 0; j < 4; ++j) {
            const unsigned short* s = WcT + (size_t)brow[j] * 768 + ks * 64 + bcsw[j] * 8;
            gload16(s, B_lds(buf) + (size_t)(j * 512 + wbase) * 8);
        }
    };

    f32x4 acc[4][4];
    #pragma unroll
    for (int m = 0; m < 4; m++)
        #pragma unroll
        for (int n = 0; n < 4; n++)
            acc[m][n] = (f32x4){0.f, 0.f, 0.f, 0.f};

    stage(0, 0);
    stage(1, 1);

    #pragma unroll
    for (int ks = 0; ks < 12; ++ks) {
        const int buf = ks & 1;
        if (ks < 11) { asm volatile("s_waitcnt vmcnt(6)" ::: "memory"); }
        else         { asm volatile("s_waitcnt vmcnt(0)" ::: "memory"); }
        __builtin_amdgcn_s_barrier();
        __builtin_amdgcn_sched_barrier(0);
        const unsigned short* Ab = A_lds(buf);
        const unsigned short* Bb = B_lds(buf);
        #pragma unroll
        for (int h = 0; h < 2; ++h) {
            short8 av[4], bv[4];
            #pragma unroll
            for (int m = 0; m < 4; m++)
                av[m] = *(const short8*)&Ab[(size_t)((wm * 64 + m * 16 + lr) * 8 + ((h * 4 + qk) ^ sxr)) * 8];
            #pragma unroll
            for (int n = 0; n < 4; n++)
                bv[n] = *(const short8*)&Bb[(size_t)((wn * 64 + n * 16 + lr) * 8 + ((h * 4 + qk) ^ sxr)) * 8];
            #pragma unroll
            for (int m = 0; m < 4; m++)
                #pragma unroll
                for (int n = 0; n < 4; n++)
                    acc[m][n] = __builtin_amdgcn_mfma_f32_16x16x32_bf16(av[m], bv[n], acc[m][n], 0, 0, 0);
        }
        __builtin_amdgcn_sched_barrier(0);
        __builtin_amdgcn_s_barrier();
        __builtin_amdgcn_sched_barrier(0);
        if (ks + 2 < 12) stage(buf, ks + 2);
    }

    // ---- epilogue: h = acc/3 + bias (bf16), LDS-staged coalesced store, BN partials ----
    unsigned short* Cst = (unsigned short*)smem;     // [64][264] ushort = 33792 B
    float* bs = (float*)(smem + 34816);              // 512 floats
    bs[t] = 0.f;
    __syncthreads();

    const float inv3 = 1.f / 3.f;
    float bco[4];
    #pragma unroll
    for (int n = 0; n < 4; n++) bco[n] = bias[wn * 64 + n * 16 + lr];

    float s[4]  = {0.f, 0.f, 0.f, 0.f};
    float s2[4] = {0.f, 0.f, 0.f, 0.f};

    #pragma unroll
    for (int p = 0; p < 2; ++p) {
        if (wm == p) {
            #pragma unroll
            for (int m = 0; m < 4; m++) {
                #pragma unroll
                for (int n = 0; n < 4; n++) {
                    const int col = wn * 64 + n * 16 + lr;
                    #pragma unroll
                    for (int j = 0; j < 4; j++) {
                        int rl = m * 16 + qk * 4 + j;
                        float h = acc[m][n][j] * inv3 + bco[n];
                        if (m0 + p * 64 + rl < V_N) { s[n] += h; s2[n] += h * h; }
                        Cst[rl * 264 + col] = f2bf(h);
                    }
                }
            }
        }
        __syncthreads();
        #pragma unroll
        for (int i = 0; i < 4; ++i) {
            int f = t + i * 512;            // 0..2047 chunks of 8 ushorts
            int row = f >> 5;
            int c8  = (f & 31) * 8;
            int r = m0 + p * 64 + row;
            if (r < V_N) {
                uint4 val = *(const uint4*)&Cst[row * 264 + c8];
                *(uint4*)&Ap[(size_t)r * 512 + c8] = val;
            }
        }
        __syncthreads();
    }

    #pragma unroll
    for (int n = 0; n < 4; n++) {
        s[n]  += __shfl_xor(s[n], 16);  s[n]  += __shfl_xor(s[n], 32);
        s2[n] += __shfl_xor(s2[n], 16); s2[n] += __shfl_xor(s2[n], 32);
    }
    if (lane < 16) {
        #pragma unroll
        for (int n = 0; n < 4; n++) {
            const int col = wn * 64 + n * 16 + lr;
            atomicAdd(&bs[col], s[n]);
            atomicAdd(&bs[256 + col], s2[n]);
        }
    }
    __syncthreads();
    partial[(size_t)blockIdx.x * 512 + t] = bs[t];
}

// ---------------- BN reduce + finalize + normalize ----------------

__global__ void bn_reduce_part(const float* __restrict__ partial, float* __restrict__ sums) {
    int t = threadIdx.x;                       // 512
    int b0 = blockIdx.x * 196;
    int b1 = b0 + 196; if (b1 > MTILES) b1 = MTILES;
    float S = 0.f;
    for (int b = b0; b < b1; b++) S += partial[(size_t)b * 512 + t];
    atomicAdd(&sums[t], S);
}

__global__ void bn_finalize(const float* __restrict__ sums, float* __restrict__ ms) {
    int c = threadIdx.x;                       // 256
    float mean = sums[c] / (float)V_N;
    float var  = sums[256 + c] / (float)V_N - mean * mean;
    ms[c]       = mean;
    ms[256 + c] = rsqrtf(var + BN_EPS);
}

// read h (bf16, Apre rows), write normalized f32 out
__global__ void bn_norm2(const unsigned short* __restrict__ hbf,
                         const float* __restrict__ ms, float* __restrict__ out) {
    const size_t total8 = (size_t)V_N * 32;    // chunks of 8 elems
    size_t stride = (size_t)gridDim.x * blockDim.x;
    for (size_t idx = (size_t)blockIdx.x * blockDim.x + threadIdx.x; idx < total8; idx += stride) {
        size_t v  = idx >> 5;
        int   c8  = (int)(idx & 31) * 8;
        uint4 uv = *(const uint4*)&hbf[v * 512 + c8];
        float4 ma = *(const float4*)&ms[c8];
        float4 mb = *(const float4*)&ms[c8 + 4];
        float4 ra = *(const float4*)&ms[256 + c8];
        float4 rb = *(const float4*)&ms[256 + c8 + 4];
        unsigned int w0 = uv.x, w1 = uv.y, w2 = uv.z, w3 = uv.w;
        float4 h0, h1;
        h0.x = (blo(w0) - ma.x) * ra.x;
        h0.y = (bhi(w0) - ma.y) * ra.y;
        h0.z = (blo(w1) - ma.z) * ra.z;
        h0.w = (bhi(w1) - ma.w) * ra.w;
        h1.x = (blo(w2) - mb.x) * rb.x;
        h1.y = (bhi(w2) - mb.y) * rb.y;
        h1.z = (blo(w3) - mb.z) * rb.z;
        h1.w = (bhi(w3) - mb.w) * rb.w;
        float* o = out + v * 256 + c8;
        *(float4*)o       = h0;
        *(float4*)(o + 4) = h1;
    }
}

__global__ void rel_out_kernel(const float* __restrict__ rel_repr,
                               const float* __restrict__ loop_rel,
                               const float* __restrict__ w_rel,
                               float* __restrict__ out)
{
    int r = blockIdx.x;
    const float* row = (r < NREL2) ? (rel_repr + (size_t)r * IN_C) : loop_rel;
    int l = threadIdx.x;
    float s = 0.f;
    #pragma unroll
    for (int q = 0; q < 4; q++) {
        int k = l + q * 64;
        s += row[k] * w_rel[(size_t)k * OUT_C + (OUT_C - 1)];
    }
    #pragma unroll
    for (int m = 32; m >= 1; m >>= 1) s += __shfl_xor(s, m);
    if (l == 0) out[(size_t)V_N * OUT_C + r] = s;
}

// ---------------- launch ----------------

extern "C" void kernel_launch(void* const* d_in, const int* in_sizes, int n_in,
                              void* d_out, int out_size, void* d_ws, size_t ws_size,
                              hipStream_t stream) {
    const float* x        = (const float*)d_in[0];
    const float* rel_repr = (const float*)d_in[1];
    const float* w        = (const float*)d_in[2];
    const float* w_rel    = (const float*)d_in[3];
    const float* loop_rel = (const float*)d_in[4];
    const float* bias     = (const float*)d_in[5];
    const int*   src      = (const int*)d_in[6];
    const int*   dst      = (const int*)d_in[7];
    const int*   etype    = (const int*)d_in[8];
    const int*   edir     = (const int*)d_in[9];
    float* out = (float*)d_out;
    unsigned short* xbf = (unsigned short*)d_out;   // [V][256] bf16 scratch (dead after GEMM)

    // workspace layout (105.60 MB, within round-2-proven bound)
    char* wsb = (char*)d_ws;
    int*   cnt     = (int*)(wsb + 0);              // 400,000
    int*   cursor  = (int*)(wsb + 400000);         // 400,000 (dead after scatter)
    unsigned short* relbf = (unsigned short*)(wsb + 400000);  // 242,688 (reuses cursor)
    int*   offs    = (int*)(wsb + 800000);         // 400,000
    float* degi    = (float*)(wsb + 1200000);      // 400,000
    int*   bsum    = (int*)(wsb + 1600000);        // 392
    float* partial = (float*)(wsb + 0);            // alias region0 (1,601,536 < 1,601,792)
    int*   epack   = (int*)(wsb + 1601792);        // 1,200,000
    float* ms      = (float*)(wsb + 2801792);      // 2048
    float* sums    = (float*)(wsb + 2803840);      // 2048
    unsigned short* WcT  = (unsigned short*)(wsb + 2805888);   // 393,216
    unsigned short* Apre = (unsigned short*)(wsb + 3199104);   // 102,400,000

    hipMemsetAsync(wsb, 0, 800000, stream);        // cnt + cursor
    hipMemsetAsync(sums, 0, 2048, stream);

    count_kernel<<<(E_N + 255) / 256, 256, 0, stream>>>(dst, cnt);
    scan1<<<NB_SCAN, 1024, 0, stream>>>(cnt, bsum, degi);
    scan2<<<1, 128, 0, stream>>>(bsum);
    scan3<<<NB_SCAN, 1024, 0, stream>>>(cnt, bsum, offs);
    scatter_kernel<<<(E_N + 255) / 256, 256, 0, stream>>>(dst, src, etype, edir,
                                                          offs, cursor, epack);
    convert_w<<<768, 256, 0, stream>>>(w, loop_rel, WcT);
    convert_x<<<2048, 256, 0, stream>>>(x, xbf);
    convert_rel<<<(NREL2 * 32 + 255) / 256, 256, 0, stream>>>(rel_repr, relbf);
    aggregate<<<(V_N * 32 + 255) / 256, 256, 0, stream>>>(xbf, relbf, degi, cnt, offs,
                                                          epack, Apre);
    mfma_gemm<<<MTILES, 512, 0, stream>>>(Apre, xbf, WcT, bias, partial);
    bn_reduce_part<<<4, 512, 0, stream>>>(partial, sums);
    bn_finalize<<<1, 256, 0, stream>>>(sums, ms);
    bn_norm2<<<2048, 256, 0, stream>>>(Apre, ms, out);
    rel_out_kernel<<<NREL2 + 1, 64, 0, stream>>>(rel_repr, loop_rel, w_rel, out);
}

// Round 9
// 268.974 us; speedup vs baseline: 1.2695x; 1.0257x over previous
//
#include <hip/hip_runtime.h>

#define V_N   100000
#define E_N   300000
#define IN_C  256
#define OUT_C 256
#define NREL2 474
#define BN_EPS 1e-5f
#define NB_SCAN 98            // ceil(V_N/1024)
#define MTILES 782            // ceil(V_N/128)

typedef __attribute__((ext_vector_type(8))) short short8;
typedef __attribute__((ext_vector_type(4))) float f32x4;

__device__ __forceinline__ unsigned short f2bf(float f) {
    unsigned int u = __builtin_bit_cast(unsigned int, f);
    u += 0x7FFFu + ((u >> 16) & 1u);          // RNE
    return (unsigned short)(u >> 16);
}
__device__ __forceinline__ unsigned int pk2bf(float lo, float hi) {
    return (unsigned int)f2bf(lo) | ((unsigned int)f2bf(hi) << 16);
}
__device__ __forceinline__ float blo(unsigned int u) {
    return __builtin_bit_cast(float, u << 16);
}
__device__ __forceinline__ float bhi(unsigned int u) {
    return __builtin_bit_cast(float, u & 0xFFFF0000u);
}

typedef const __attribute__((address_space(1))) unsigned int* gas1_t;
typedef __attribute__((address_space(3))) unsigned int* las3_t;
__device__ __forceinline__ void gload16(const void* g, void* l) {
    __builtin_amdgcn_global_load_lds((gas1_t)g, (las3_t)l, 16, 0, 0);
}

// ---------------- CSR build ----------------

__global__ void count_kernel(const int* __restrict__ dst, int* __restrict__ cnt) {
    int e = blockIdx.x * 256 + threadIdx.x;
    if (e < E_N) atomicAdd(&cnt[dst[e]], 1);
}

// coalesced per-block sums; also emits degi = rsqrt(cnt)
__global__ __launch_bounds__(1024)
void scan1(const int* __restrict__ cnt, int* __restrict__ bsum, float* __restrict__ degi) {
    __shared__ int red[1024];
    int t = threadIdx.x;
    int v = blockIdx.x * 1024 + t;
    int c = (v < V_N) ? cnt[v] : 0;
    if (v < V_N) degi[v] = c > 0 ? rsqrtf((float)c) : 0.f;
    red[t] = c;
    __syncthreads();
    for (int s = 512; s > 0; s >>= 1) {
        if (t < s) red[t] += red[t + s];
        __syncthreads();
    }
    if (t == 0) bsum[blockIdx.x] = red[0];
}

// parallel exclusive scan of the 98 block sums (one 128-thread block)
__global__ void scan2(int* bsum) {
    __shared__ int sc[128];
    int t = threadIdx.x;
    int v = (t < NB_SCAN) ? bsum[t] : 0;
    sc[t] = v;
    __syncthreads();
    for (int d = 1; d < 128; d <<= 1) {
        int add = (t >= d) ? sc[t - d] : 0;
        __syncthreads();
        sc[t] += add;
        __syncthreads();
    }
    if (t < NB_SCAN) bsum[t] = sc[t] - v;   // exclusive
}

__global__ __launch_bounds__(1024)
void scan3(const int* __restrict__ cnt, const int* __restrict__ bsum,
           int* __restrict__ offs) {
    __shared__ int sc[1024];
    int t = threadIdx.x;
    int v = blockIdx.x * 1024 + t;
    int c = (v < V_N) ? cnt[v] : 0;
    sc[t] = c;
    __syncthreads();
    for (int d = 1; d < 1024; d <<= 1) {
        int add = (t >= d) ? sc[t - d] : 0;
        __syncthreads();
        sc[t] += add;
        __syncthreads();
    }
    if (v < V_N) offs[v] = sc[t] - c + bsum[blockIdx.x];
}

__global__ void scatter_kernel(const int* __restrict__ dst, const int* __restrict__ src,
                               const int* __restrict__ etype, const int* __restrict__ edir,
                               const int* __restrict__ offs, int* __restrict__ cursor,
                               int* __restrict__ epack) {
    int e = blockIdx.x * 256 + threadIdx.x;
    if (e < E_N) {
        int d = dst[e];
        int pos = offs[d] + atomicAdd(&cursor[d], 1);
        epack[pos] = src[e] | (etype[e] << 17) | (edir[e] << 26);
    }
}

// WcT[n][k] = bf16(w_flat[k][n]); rows k>=512 pre-multiplied by loop_rel[k-512]
__global__ void convert_w(const float* __restrict__ w, const float* __restrict__ loop_rel,
                          unsigned short* __restrict__ WcT) {
    int k = blockIdx.x;    // 0..767
    int n = threadIdx.x;   // 0..255
    float f = w[(size_t)k * 256 + n];
    if (k >= 512) f *= loop_rel[k - 512];
    WcT[(size_t)n * 768 + k] = f2bf(f);
}

// x -> xbf (bf16, plain [V][256], lives in d_out scratch)
__global__ void convert_x(const float* __restrict__ x, unsigned short* __restrict__ xbf) {
    const size_t total8 = (size_t)V_N * 32;    // 8-elem chunks
    size_t stride = (size_t)gridDim.x * blockDim.x;
    for (size_t idx = (size_t)blockIdx.x * blockDim.x + threadIdx.x; idx < total8; idx += stride) {
        const float* s = x + idx * 8;
        float4 a = *(const float4*)s, b = *(const float4*)(s + 4);
        uint4 u;
        u.x = pk2bf(a.x, a.y); u.y = pk2bf(a.z, a.w);
        u.z = pk2bf(b.x, b.y); u.w = pk2bf(b.z, b.w);
        *(uint4*)(xbf + idx * 8) = u;
    }
}

// rel_repr -> relbf (bf16, [NREL2][256])
__global__ void convert_rel(const float* __restrict__ rel, unsigned short* __restrict__ relbf) {
    const int total8 = NREL2 * 32;
    int idx = blockIdx.x * 256 + threadIdx.x;
    if (idx < total8) {
        const float* s = rel + (size_t)idx * 8;
        float4 a = *(const float4*)s, b = *(const float4*)(s + 4);
        uint4 u;
        u.x = pk2bf(a.x, a.y); u.y = pk2bf(a.z, a.w);
        u.z = pk2bf(b.x, b.y); u.w = pk2bf(b.z, b.w);
        *(uint4*)(relbf + (size_t)idx * 8) = u;
    }
}

// ---------------- aggregate: HALF-WAVE (32 lanes) per dst node, bf16 gathers ----------------
// Apre[v][0..255]=dir0 agg, [256..511]=dir1 agg (bf16).
__global__ __launch_bounds__(256)
void aggregate(const unsigned short* __restrict__ xbf,
               const unsigned short* __restrict__ relbf,
               const float* __restrict__ degi,
               const int* __restrict__ cnt, const int* __restrict__ offs,
               const int* __restrict__ epack, unsigned short* __restrict__ Apre) {
    const int node = (blockIdx.x * 256 + threadIdx.x) >> 5;
    const int lane = threadIdx.x & 31;
    if (node >= V_N) return;
    const int v = node;
    const int n = cnt[v];
    const int base = offs[v];
    const float dv = degi[v];
    const int c8 = lane * 8;                 // this lane owns 8 elems of the row

    float a0[8] = {0,0,0,0,0,0,0,0};
    float a1[8] = {0,0,0,0,0,0,0,0};

    int i = 0;
    for (; i + 2 <= n; i += 2) {
        int p0 = epack[base + i];
        int p1 = epack[base + i + 1];
        int s0 = p0 & 0x1FFFF, s1 = p1 & 0x1FFFF;
        int t0 = (p0 >> 17) & 0x1FF, t1 = (p1 >> 17) & 0x1FF;
        float en0 = degi[s0] * dv, en1 = degi[s1] * dv;
        float e00 = (p0 & (1 << 26)) ? 0.f : en0, e01 = en0 - e00;
        float e10 = (p1 & (1 << 26)) ? 0.f : en1, e11 = en1 - e10;
        uint4 xu0 = *(const uint4*)(xbf   + (size_t)s0 * 256 + c8);
        uint4 ru0 = *(const uint4*)(relbf + (size_t)t0 * 256 + c8);
        uint4 xu1 = *(const uint4*)(xbf   + (size_t)s1 * 256 + c8);
        uint4 ru1 = *(const uint4*)(relbf + (size_t)t1 * 256 + c8);
        float m[8];
        m[0] = blo(xu0.x) * blo(ru0.x); m[1] = bhi(xu0.x) * bhi(ru0.x);
        m[2] = blo(xu0.y) * blo(ru0.y); m[3] = bhi(xu0.y) * bhi(ru0.y);
        m[4] = blo(xu0.z) * blo(ru0.z); m[5] = bhi(xu0.z) * bhi(ru0.z);
        m[6] = blo(xu0.w) * blo(ru0.w); m[7] = bhi(xu0.w) * bhi(ru0.w);
        #pragma unroll
        for (int j = 0; j < 8; j++) { a0[j] += m[j] * e00; a1[j] += m[j] * e01; }
        m[0] = blo(xu1.x) * blo(ru1.x); m[1] = bhi(xu1.x) * bhi(ru1.x);
        m[2] = blo(xu1.y) * blo(ru1.y); m[3] = bhi(xu1.y) * bhi(ru1.y);
        m[4] = blo(xu1.z) * blo(ru1.z); m[5] = bhi(xu1.z) * bhi(ru1.z);
        m[6] = blo(xu1.w) * blo(ru1.w); m[7] = bhi(xu1.w) * bhi(ru1.w);
        #pragma unroll
        for (int j = 0; j < 8; j++) { a0[j] += m[j] * e10; a1[j] += m[j] * e11; }
    }
    if (i < n) {
        int p = epack[base + i];
        int s = p & 0x1FFFF;
        int tt = (p >> 17) & 0x1FF;
        float en = degi[s] * dv;
        float e0 = (p & (1 << 26)) ? 0.f : en, e1 = en - e0;
        uint4 xu = *(const uint4*)(xbf   + (size_t)s * 256 + c8);
        uint4 ru = *(const uint4*)(relbf + (size_t)tt * 256 + c8);
        float m[8];
        m[0] = blo(xu.x) * blo(ru.x); m[1] = bhi(xu.x) * bhi(ru.x);
        m[2] = blo(xu.y) * blo(ru.y); m[3] = bhi(xu.y) * bhi(ru.y);
        m[4] = blo(xu.z) * blo(ru.z); m[5] = bhi(xu.z) * bhi(ru.z);
        m[6] = blo(xu.w) * blo(ru.w); m[7] = bhi(xu.w) * bhi(ru.w);
        #pragma unroll
        for (int j = 0; j < 8; j++) { a0[j] += m[j] * e0; a1[j] += m[j] * e1; }
    }

    uint4 u0, u1;
    u0.x = pk2bf(a0[0], a0[1]); u0.y = pk2bf(a0[2], a0[3]);
    u0.z = pk2bf(a0[4], a0[5]); u0.w = pk2bf(a0[6], a0[7]);
    u1.x = pk2bf(a1[0], a1[1]); u1.y = pk2bf(a1[2], a1[3]);
    u1.z = pk2bf(a1[4], a1[5]); u1.w = pk2bf(a1[6], a1[7]);
    *(uint4*)(Apre + (size_t)v * 512 + c8)       = u0;
    *(uint4*)(Apre + (size_t)v * 512 + 256 + c8) = u1;
}

// ---------------- fused GEMM: TRIPLE-buffer, ONE barrier per K-step ----------------
// out_h(bf16, into Apre rows) = [Apre | xbf] @ WcT^T, /3 + bias; BN col partials.
// 128 rows x 256 cols per block, 8 waves (2x4). K=768, BK=64, 12 steps.
// 3 LDS stage-buffers (A 3x16KB @0, B 3x32KB @49152 = 144KB). The buffer staged
// at step ks (for ks+2) is the one last READ at ks-1, and the top-of-step
// barrier already proves all waves finished compute ks-1 -> the post-compute
// barrier of the 2-buffer scheme is unnecessary. Stage issued BEFORE compute:
// 2 stages (12 loads) in flight under every compute phase; vmcnt(6) waits
// exactly for the current tile. Trailing __syncthreads protects smem reuse.
__global__ __launch_bounds__(512)
void mfma_gemm(unsigned short* Ap /* Apre, also h output */,
               const unsigned short* __restrict__ xbf,
               const unsigned short* __restrict__ WcT,
               const float* __restrict__ bias, float* __restrict__ partial) {
    __shared__ __align__(16) unsigned char smem[147456];

    const int t    = threadIdx.x;
    const int m0   = blockIdx.x * 128;
    const int wid  = t >> 6;
    const int lane = t & 63;
    const int wm   = wid >> 2;
    const int wn   = wid & 3;
    const int lr   = lane & 15;
    const int qk   = lane >> 4;
    const int sxr  = lr & 7;
    const int wbase = t & 0x1C0;

    // staging constants
    int arow[2], acsw[2], brow[4], bcsw[4];
    #pragma unroll
    for (int j = 0; j < 2; ++j) {
        int g = j * 512 + t;
        arow[j] = g >> 3;
        acsw[j] = (g & 7) ^ (arow[j] & 7);
    }
    #pragma unroll
    for (int j = 0; j < 4; ++j) {
        int g = j * 512 + t;
        brow[j] = g >> 3;
        bcsw[j] = (g & 7) ^ (brow[j] & 7);
    }

    auto A_lds = [&](int buf) { return (unsigned short*)(smem + buf * 16384); };
    auto B_lds = [&](int buf) { return (unsigned short*)(smem + 49152 + buf * 32768); };

    auto stage = [&](int buf, int ks) {
        #pragma unroll
        for (int j = 0; j < 2; ++j) {
            int rg = m0 + arow[j];
            if (rg >= V_N) rg = V_N - 1;
            const unsigned short* s = (ks < 8)
                ? Ap  + (size_t)rg * 512 + ks * 64 + acsw[j] * 8
                : xbf + (size_t)rg * 256 + (ks - 8) * 64 + acsw[j] * 8;
            gload16(s, A_lds(buf) + (size_t)(j * 512 + wbase) * 8);
        }
        #pragma unroll
        for (int j = 0; j < 4; ++j) {
            const unsigned short* s = WcT + (size_t)brow[j] * 768 + ks * 64 + bcsw[j] * 8;
            gload16(s, B_lds(buf) + (size_t)(j * 512 + wbase) * 8);
        }
    };

    f32x4 acc[4][4];
    #pragma unroll
    for (int m = 0; m < 4; m++)
        #pragma unroll
        for (int n = 0; n < 4; n++)
            acc[m][n] = (f32x4){0.f, 0.f, 0.f, 0.f};

    stage(0, 0);
    stage(1, 1);

    #pragma unroll
    for (int ks = 0; ks < 12; ++ks) {
        const int buf = ks % 3;
        if (ks < 11) { asm volatile("s_waitcnt vmcnt(6)" ::: "memory"); }
        else         { asm volatile("s_waitcnt vmcnt(0)" ::: "memory"); }
        __builtin_amdgcn_s_barrier();
        __builtin_amdgcn_sched_barrier(0);
        if (ks + 2 < 12) stage((ks + 2) % 3, ks + 2);   // issue-early: overlaps compute
        __builtin_amdgcn_sched_barrier(0);
        const unsigned short* Ab = A_lds(buf);
        const unsigned short* Bb = B_lds(buf);
        #pragma unroll
        for (int h = 0; h < 2; ++h) {
            short8 av[4], bv[4];
            #pragma unroll
            for (int m = 0; m < 4; m++)
                av[m] = *(const short8*)&Ab[(size_t)((wm * 64 + m * 16 + lr) * 8 + ((h * 4 + qk) ^ sxr)) * 8];
            #pragma unroll
            for (int n = 0; n < 4; n++)
                bv[n] = *(const short8*)&Bb[(size_t)((wn * 64 + n * 16 + lr) * 8 + ((h * 4 + qk) ^ sxr)) * 8];
            #pragma unroll
            for (int m = 0; m < 4; m++)
                #pragma unroll
                for (int n = 0; n < 4; n++)
                    acc[m][n] = __builtin_amdgcn_mfma_f32_16x16x32_bf16(av[m], bv[n], acc[m][n], 0, 0, 0);
        }
    }
    __syncthreads();   // all waves done with LDS tiles before epilogue reuses smem

    // ---- epilogue: h = acc/3 + bias (bf16), LDS-staged coalesced store, BN partials ----
    unsigned short* Cst = (unsigned short*)smem;     // [64][264] ushort = 33792 B
    float* bs = (float*)(smem + 34816);              // 512 floats
    bs[t] = 0.f;
    __syncthreads();

    const float inv3 = 1.f / 3.f;
    float bco[4];
    #pragma unroll
    for (int n = 0; n < 4; n++) bco[n] = bias[wn * 64 + n * 16 + lr];

    float s[4]  = {0.f, 0.f, 0.f, 0.f};
    float s2[4] = {0.f, 0.f, 0.f, 0.f};

    #pragma unroll
    for (int p = 0; p < 2; ++p) {
        if (wm == p) {
            #pragma unroll
            for (int m = 0; m < 4; m++) {
                #pragma unroll
                for (int n = 0; n < 4; n++) {
                    const int col = wn * 64 + n * 16 + lr;
                    #pragma unroll
                    for (int j = 0; j < 4; j++) {
                        int rl = m * 16 + qk * 4 + j;
                        float h = acc[m][n][j] * inv3 + bco[n];
                        if (m0 + p * 64 + rl < V_N) { s[n] += h; s2[n] += h * h; }
                        Cst[rl * 264 + col] = f2bf(h);
                    }
                }
            }
        }
        __syncthreads();
        #pragma unroll
        for (int i = 0; i < 4; ++i) {
            int f = t + i * 512;            // 0..2047 chunks of 8 ushorts
            int row = f >> 5;
            int c8  = (f & 31) * 8;
            int r = m0 + p * 64 + row;
            if (r < V_N) {
                uint4 val = *(const uint4*)&Cst[row * 264 + c8];
                *(uint4*)&Ap[(size_t)r * 512 + c8] = val;
            }
        }
        __syncthreads();
    }

    #pragma unroll
    for (int n = 0; n < 4; n++) {
        s[n]  += __shfl_xor(s[n], 16);  s[n]  += __shfl_xor(s[n], 32);
        s2[n] += __shfl_xor(s2[n], 16); s2[n] += __shfl_xor(s2[n], 32);
    }
    if (lane < 16) {
        #pragma unroll
        for (int n = 0; n < 4; n++) {
            const int col = wn * 64 + n * 16 + lr;
            atomicAdd(&bs[col], s[n]);
            atomicAdd(&bs[256 + col], s2[n]);
        }
    }
    __syncthreads();
    partial[(size_t)blockIdx.x * 512 + t] = bs[t];
}

// ---------------- BN reduce + finalize + normalize ----------------

__global__ void bn_reduce_part(const float* __restrict__ partial, float* __restrict__ sums) {
    int t = threadIdx.x;                       // 512
    int b0 = blockIdx.x * 196;
    int b1 = b0 + 196; if (b1 > MTILES) b1 = MTILES;
    float S = 0.f;
    for (int b = b0; b < b1; b++) S += partial[(size_t)b * 512 + t];
    atomicAdd(&sums[t], S);
}

__global__ void bn_finalize(const float* __restrict__ sums, float* __restrict__ ms) {
    int c = threadIdx.x;                       // 256
    float mean = sums[c] / (float)V_N;
    float var  = sums[256 + c] / (float)V_N - mean * mean;
    ms[c]       = mean;
    ms[256 + c] = rsqrtf(var + BN_EPS);
}

// read h (bf16, Apre rows), write normalized f32 out
__global__ void bn_norm2(const unsigned short* __restrict__ hbf,
                         const float* __restrict__ ms, float* __restrict__ out) {
    const size_t total8 = (size_t)V_N * 32;    // chunks of 8 elems
    size_t stride = (size_t)gridDim.x * blockDim.x;
    for (size_t idx = (size_t)blockIdx.x * blockDim.x + threadIdx.x; idx < total8; idx += stride) {
        size_t v  = idx >> 5;
        int   c8  = (int)(idx & 31) * 8;
        uint4 uv = *(const uint4*)&hbf[v * 512 + c8];
        float4 ma = *(const float4*)&ms[c8];
        float4 mb = *(const float4*)&ms[c8 + 4];
        float4 ra = *(const float4*)&ms[256 + c8];
        float4 rb = *(const float4*)&ms[256 + c8 + 4];
        unsigned int w0 = uv.x, w1 = uv.y, w2 = uv.z, w3 = uv.w;
        float4 h0, h1;
        h0.x = (blo(w0) - ma.x) * ra.x;
        h0.y = (bhi(w0) - ma.y) * ra.y;
        h0.z = (blo(w1) - ma.z) * ra.z;
        h0.w = (bhi(w1) - ma.w) * ra.w;
        h1.x = (blo(w2) - mb.x) * rb.x;
        h1.y = (bhi(w2) - mb.y) * rb.y;
        h1.z = (blo(w3) - mb.z) * rb.z;
        h1.w = (bhi(w3) - mb.w) * rb.w;
        float* o = out + v * 256 + c8;
        *(float4*)o       = h0;
        *(float4*)(o + 4) = h1;
    }
}

__global__ void rel_out_kernel(const float* __restrict__ rel_repr,
                               const float* __restrict__ loop_rel,
                               const float* __restrict__ w_rel,
                               float* __restrict__ out)
{
    int r = blockIdx.x;
    const float* row = (r < NREL2) ? (rel_repr + (size_t)r * IN_C) : loop_rel;
    int l = threadIdx.x;
    float s = 0.f;
    #pragma unroll
    for (int q = 0; q < 4; q++) {
        int k = l + q * 64;
        s += row[k] * w_rel[(size_t)k * OUT_C + (OUT_C - 1)];
    }
    #pragma unroll
    for (int m = 32; m >= 1; m >>= 1) s += __shfl_xor(s, m);
    if (l == 0) out[(size_t)V_N * OUT_C + r] = s;
}

// ---------------- launch ----------------

extern "C" void kernel_launch(void* const* d_in, const int* in_sizes, int n_in,
                              void* d_out, int out_size, void* d_ws, size_t ws_size,
                              hipStream_t stream) {
    const float* x        = (const float*)d_in[0];
    const float* rel_repr = (const float*)d_in[1];
    const float* w        = (const float*)d_in[2];
    const float* w_rel    = (const float*)d_in[3];
    const float* loop_rel = (const float*)d_in[4];
    const float* bias     = (const float*)d_in[5];
    const int*   src      = (const int*)d_in[6];
    const int*   dst      = (const int*)d_in[7];
    const int*   etype    = (const int*)d_in[8];
    const int*   edir     = (const int*)d_in[9];
    float* out = (float*)d_out;
    unsigned short* xbf = (unsigned short*)d_out;   // [V][256] bf16 scratch (dead after GEMM)

    // workspace layout (105.60 MB, within round-2-proven bound)
    char* wsb = (char*)d_ws;
    int*   cnt     = (int*)(wsb + 0);              // 400,000
    int*   cursor  = (int*)(wsb + 400000);         // 400,000 (dead after scatter)
    unsigned short* relbf = (unsigned short*)(wsb + 400000);  // 242,688 (reuses cursor)
    int*   offs    = (int*)(wsb + 800000);         // 400,000
    float* degi    = (float*)(wsb + 1200000);      // 400,000
    int*   bsum    = (int*)(wsb + 1600000);        // 392
    float* partial = (float*)(wsb + 0);            // alias region0 (1,601,536 < 1,601,792)
    int*   epack   = (int*)(wsb + 1601792);        // 1,200,000
    float* ms      = (float*)(wsb + 2801792);      // 2048
    float* sums    = (float*)(wsb + 2803840);      // 2048
    unsigned short* WcT  = (unsigned short*)(wsb + 2805888);   // 393,216
    unsigned short* Apre = (unsigned short*)(wsb + 3199104);   // 102,400,000

    hipMemsetAsync(wsb, 0, 800000, stream);        // cnt + cursor
    hipMemsetAsync(sums, 0, 2048, stream);

    count_kernel<<<(E_N + 255) / 256, 256, 0, stream>>>(dst, cnt);
    scan1<<<NB_SCAN, 1024, 0, stream>>>(cnt, bsum, degi);
    scan2<<<1, 128, 0, stream>>>(bsum);
    scan3<<<NB_SCAN, 1024, 0, stream>>>(cnt, bsum, offs);
    scatter_kernel<<<(E_N + 255) / 256, 256, 0, stream>>>(dst, src, etype, edir,
                                                          offs, cursor, epack);
    convert_w<<<768, 256, 0, stream>>>(w, loop_rel, WcT);
    convert_x<<<2048, 256, 0, stream>>>(x, xbf);
    convert_rel<<<(NREL2 * 32 + 255) / 256, 256, 0, stream>>>(rel_repr, relbf);
    aggregate<<<(V_N * 32 + 255) / 256, 256, 0, stream>>>(xbf, relbf, degi, cnt, offs,
                                                          epack, Apre);
    mfma_gemm<<<MTILES, 512, 0, stream>>>(Apre, xbf, WcT, bias, partial);
    bn_reduce_part<<<4, 512, 0, stream>>>(partial, sums);
    bn_finalize<<<1, 256, 0, stream>>>(sums, ms);
    bn_norm2<<<2048, 256, 0, stream>>>(Apre, ms, out);
    rel_out_kernel<<<NREL2 + 1, 64, 0, stream>>>(rel_repr, loop_rel, w_rel, out);
}

// Round 10
// 250.377 us; speedup vs baseline: 1.3638x; 1.0743x over previous
//
#include <hip/hip_runtime.h>

#define V_N   100000
#define E_N   300000
#define IN_C  256
#define OUT_C 256
#define NREL2 474
#define BN_EPS 1e-5f
#define NB_SCAN 98            // ceil(V_N/1024)
#define MTILES 391            // ceil(V_N/256)
#define BRCHUNK 98            // ceil(MTILES/4)

typedef __attribute__((ext_vector_type(8))) short short8;
typedef __attribute__((ext_vector_type(4))) float f32x4;

__device__ __forceinline__ unsigned short f2bf(float f) {
    unsigned int u = __builtin_bit_cast(unsigned int, f);
    u += 0x7FFFu + ((u >> 16) & 1u);          // RNE
    return (unsigned short)(u >> 16);
}
__device__ __forceinline__ unsigned int pk2bf(float lo, float hi) {
    return (unsigned int)f2bf(lo) | ((unsigned int)f2bf(hi) << 16);
}
__device__ __forceinline__ float blo(unsigned int u) {
    return __builtin_bit_cast(float, u << 16);
}
__device__ __forceinline__ float bhi(unsigned int u) {
    return __builtin_bit_cast(float, u & 0xFFFF0000u);
}

typedef const __attribute__((address_space(1))) unsigned int* gas1_t;
typedef __attribute__((address_space(3))) unsigned int* las3_t;
__device__ __forceinline__ void gload16(const void* g, void* l) {
    __builtin_amdgcn_global_load_lds((gas1_t)g, (las3_t)l, 16, 0, 0);
}

// ---------------- CSR build ----------------

__global__ void count_kernel(const int* __restrict__ dst, int* __restrict__ cnt) {
    int e = blockIdx.x * 256 + threadIdx.x;
    if (e < E_N) atomicAdd(&cnt[dst[e]], 1);
}

// coalesced per-block sums; also emits degi = rsqrt(cnt)
__global__ __launch_bounds__(1024)
void scan1(const int* __restrict__ cnt, int* __restrict__ bsum, float* __restrict__ degi) {
    __shared__ int red[1024];
    int t = threadIdx.x;
    int v = blockIdx.x * 1024 + t;
    int c = (v < V_N) ? cnt[v] : 0;
    if (v < V_N) degi[v] = c > 0 ? rsqrtf((float)c) : 0.f;
    red[t] = c;
    __syncthreads();
    for (int s = 512; s > 0; s >>= 1) {
        if (t < s) red[t] += red[t + s];
        __syncthreads();
    }
    if (t == 0) bsum[blockIdx.x] = red[0];
}

// parallel exclusive scan of the 98 block sums (one 128-thread block)
__global__ void scan2(int* bsum) {
    __shared__ int sc[128];
    int t = threadIdx.x;
    int v = (t < NB_SCAN) ? bsum[t] : 0;
    sc[t] = v;
    __syncthreads();
    for (int d = 1; d < 128; d <<= 1) {
        int add = (t >= d) ? sc[t - d] : 0;
        __syncthreads();
        sc[t] += add;
        __syncthreads();
    }
    if (t < NB_SCAN) bsum[t] = sc[t] - v;   // exclusive
}

__global__ __launch_bounds__(1024)
void scan3(const int* __restrict__ cnt, const int* __restrict__ bsum,
           int* __restrict__ offs) {
    __shared__ int sc[1024];
    int t = threadIdx.x;
    int v = blockIdx.x * 1024 + t;
    int c = (v < V_N) ? cnt[v] : 0;
    sc[t] = c;
    __syncthreads();
    for (int d = 1; d < 1024; d <<= 1) {
        int add = (t >= d) ? sc[t - d] : 0;
        __syncthreads();
        sc[t] += add;
        __syncthreads();
    }
    if (v < V_N) offs[v] = sc[t] - c + bsum[blockIdx.x];
}

__global__ void scatter_kernel(const int* __restrict__ dst, const int* __restrict__ src,
                               const int* __restrict__ etype, const int* __restrict__ edir,
                               const int* __restrict__ offs, int* __restrict__ cursor,
                               int* __restrict__ epack) {
    int e = blockIdx.x * 256 + threadIdx.x;
    if (e < E_N) {
        int d = dst[e];
        int pos = offs[d] + atomicAdd(&cursor[d], 1);
        epack[pos] = src[e] | (etype[e] << 17) | (edir[e] << 26);
    }
}

// WcT[n][k] = bf16(w_flat[k][n]); rows k>=512 pre-multiplied by loop_rel[k-512]
__global__ void convert_w(const float* __restrict__ w, const float* __restrict__ loop_rel,
                          unsigned short* __restrict__ WcT) {
    int k = blockIdx.x;    // 0..767
    int n = threadIdx.x;   // 0..255
    float f = w[(size_t)k * 256 + n];
    if (k >= 512) f *= loop_rel[k - 512];
    WcT[(size_t)n * 768 + k] = f2bf(f);
}

// x -> xbf (bf16, plain [V][256], lives in d_out scratch)
__global__ void convert_x(const float* __restrict__ x, unsigned short* __restrict__ xbf) {
    const size_t total8 = (size_t)V_N * 32;    // 8-elem chunks
    size_t stride = (size_t)gridDim.x * blockDim.x;
    for (size_t idx = (size_t)blockIdx.x * blockDim.x + threadIdx.x; idx < total8; idx += stride) {
        const float* s = x + idx * 8;
        float4 a = *(const float4*)s, b = *(const float4*)(s + 4);
        uint4 u;
        u.x = pk2bf(a.x, a.y); u.y = pk2bf(a.z, a.w);
        u.z = pk2bf(b.x, b.y); u.w = pk2bf(b.z, b.w);
        *(uint4*)(xbf + idx * 8) = u;
    }
}

// rel_repr -> relbf (bf16, [NREL2][256])
__global__ void convert_rel(const float* __restrict__ rel, unsigned short* __restrict__ relbf) {
    const int total8 = NREL2 * 32;
    int idx = blockIdx.x * 256 + threadIdx.x;
    if (idx < total8) {
        const float* s = rel + (size_t)idx * 8;
        float4 a = *(const float4*)s, b = *(const float4*)(s + 4);
        uint4 u;
        u.x = pk2bf(a.x, a.y); u.y = pk2bf(a.z, a.w);
        u.z = pk2bf(b.x, b.y); u.w = pk2bf(b.z, b.w);
        *(uint4*)(relbf + (size_t)idx * 8) = u;
    }
}

// ---------------- aggregate: HALF-WAVE (32 lanes) per dst node, bf16 gathers ----------------
// Apre[v][0..255]=dir0 agg, [256..511]=dir1 agg (bf16).
__global__ __launch_bounds__(256)
void aggregate(const unsigned short* __restrict__ xbf,
               const unsigned short* __restrict__ relbf,
               const float* __restrict__ degi,
               const int* __restrict__ cnt, const int* __restrict__ offs,
               const int* __restrict__ epack, unsigned short* __restrict__ Apre) {
    const int node = (blockIdx.x * 256 + threadIdx.x) >> 5;
    const int lane = threadIdx.x & 31;
    if (node >= V_N) return;
    const int v = node;
    const int n = cnt[v];
    const int base = offs[v];
    const float dv = degi[v];
    const int c8 = lane * 8;                 // this lane owns 8 elems of the row

    float a0[8] = {0,0,0,0,0,0,0,0};
    float a1[8] = {0,0,0,0,0,0,0,0};

    int i = 0;
    for (; i + 2 <= n; i += 2) {
        int p0 = epack[base + i];
        int p1 = epack[base + i + 1];
        int s0 = p0 & 0x1FFFF, s1 = p1 & 0x1FFFF;
        int t0 = (p0 >> 17) & 0x1FF, t1 = (p1 >> 17) & 0x1FF;
        float en0 = degi[s0] * dv, en1 = degi[s1] * dv;
        float e00 = (p0 & (1 << 26)) ? 0.f : en0, e01 = en0 - e00;
        float e10 = (p1 & (1 << 26)) ? 0.f : en1, e11 = en1 - e10;
        uint4 xu0 = *(const uint4*)(xbf   + (size_t)s0 * 256 + c8);
        uint4 ru0 = *(const uint4*)(relbf + (size_t)t0 * 256 + c8);
        uint4 xu1 = *(const uint4*)(xbf   + (size_t)s1 * 256 + c8);
        uint4 ru1 = *(const uint4*)(relbf + (size_t)t1 * 256 + c8);
        float m[8];
        m[0] = blo(xu0.x) * blo(ru0.x); m[1] = bhi(xu0.x) * bhi(ru0.x);
        m[2] = blo(xu0.y) * blo(ru0.y); m[3] = bhi(xu0.y) * bhi(ru0.y);
        m[4] = blo(xu0.z) * blo(ru0.z); m[5] = bhi(xu0.z) * bhi(ru0.z);
        m[6] = blo(xu0.w) * blo(ru0.w); m[7] = bhi(xu0.w) * bhi(ru0.w);
        #pragma unroll
        for (int j = 0; j < 8; j++) { a0[j] += m[j] * e00; a1[j] += m[j] * e01; }
        m[0] = blo(xu1.x) * blo(ru1.x); m[1] = bhi(xu1.x) * bhi(ru1.x);
        m[2] = blo(xu1.y) * blo(ru1.y); m[3] = bhi(xu1.y) * bhi(ru1.y);
        m[4] = blo(xu1.z) * blo(ru1.z); m[5] = bhi(xu1.z) * bhi(ru1.z);
        m[6] = blo(xu1.w) * blo(ru1.w); m[7] = bhi(xu1.w) * bhi(ru1.w);
        #pragma unroll
        for (int j = 0; j < 8; j++) { a0[j] += m[j] * e10; a1[j] += m[j] * e11; }
    }
    if (i < n) {
        int p = epack[base + i];
        int s = p & 0x1FFFF;
        int tt = (p >> 17) & 0x1FF;
        float en = degi[s] * dv;
        float e0 = (p & (1 << 26)) ? 0.f : en, e1 = en - e0;
        uint4 xu = *(const uint4*)(xbf   + (size_t)s * 256 + c8);
        uint4 ru = *(const uint4*)(relbf + (size_t)tt * 256 + c8);
        float m[8];
        m[0] = blo(xu.x) * blo(ru.x); m[1] = bhi(xu.x) * bhi(ru.x);
        m[2] = blo(xu.y) * blo(ru.y); m[3] = bhi(xu.y) * bhi(ru.y);
        m[4] = blo(xu.z) * blo(ru.z); m[5] = bhi(xu.z) * bhi(ru.z);
        m[6] = blo(xu.w) * blo(ru.w); m[7] = bhi(xu.w) * bhi(ru.w);
        #pragma unroll
        for (int j = 0; j < 8; j++) { a0[j] += m[j] * e0; a1[j] += m[j] * e1; }
    }

    uint4 u0, u1;
    u0.x = pk2bf(a0[0], a0[1]); u0.y = pk2bf(a0[2], a0[3]);
    u0.z = pk2bf(a0[4], a0[5]); u0.w = pk2bf(a0[6], a0[7]);
    u1.x = pk2bf(a1[0], a1[1]); u1.y = pk2bf(a1[2], a1[3]);
    u1.z = pk2bf(a1[4], a1[5]); u1.w = pk2bf(a1[6], a1[7]);
    *(uint4*)(Apre + (size_t)v * 512 + c8)       = u0;
    *(uint4*)(Apre + (size_t)v * 512 + 256 + c8) = u1;
}

// ---------------- fused GEMM: 256x256 tile, dbuf, ONE barrier per K-step ----------------
// out_h(bf16, into Apre rows) = [Apre | xbf] @ WcT^T, /3 + bias; BN col partials.
// 256 rows x 256 cols per block, 8 waves (4 row-groups x 2 col-groups), wave
// tile 64x128 (acc[4][8]). K=768, BK=64, 12 steps. LDS: A dbuf 2x32KB @0,
// B dbuf 2x32KB @65536 (128KB). Single barrier per step: stage(ks+1) is issued
// right after the top-of-step barrier (which proves compute ks-1 done, i.e. the
// target buffer is free); vmcnt(0) at top waits only for loads that had a full
// compute phase (~1240cy SIMD) to land. Halves B logical traffic vs 128-tile
// (391 blocks x 393KB) and doubles MFMA per barrier (64/wave/step).
__global__ __launch_bounds__(512)
void mfma_gemm(unsigned short* Ap /* Apre, also h output */,
               const unsigned short* __restrict__ xbf,
               const unsigned short* __restrict__ WcT,
               const float* __restrict__ bias, float* __restrict__ partial) {
    __shared__ __align__(16) unsigned char smem[131072];

    const int t    = threadIdx.x;
    const int m0   = blockIdx.x * 256;
    const int wid  = t >> 6;
    const int lane = t & 63;
    const int wm   = wid >> 1;          // 0..3 row-group
    const int wn   = wid & 1;           // 0..1 col-group
    const int lr   = lane & 15;
    const int qk   = lane >> 4;
    const int sxr  = lr & 7;
    const int wbase = t & 0x1C0;

    // staging constants: 2048 chunks each for A and B, 4 per thread
    int arow[4], acsw[4], brow[4], bcsw[4];
    #pragma unroll
    for (int j = 0; j < 4; ++j) {
        int g = j * 512 + t;
        arow[j] = g >> 3;               // 0..255 row
        acsw[j] = (g & 7) ^ (arow[j] & 7);
        brow[j] = g >> 3;               // 0..255 col
        bcsw[j] = (g & 7) ^ (brow[j] & 7);
    }

    auto A_lds = [&](int buf) { return (unsigned short*)(smem + buf * 32768); };
    auto B_lds = [&](int buf) { return (unsigned short*)(smem + 65536 + buf * 32768); };

    auto stage = [&](int buf, int ks) {
        #pragma unroll
        for (int j = 0; j < 4; ++j) {
            int rg = m0 + arow[j];
            if (rg >= V_N) rg = V_N - 1;
            const unsigned short* s = (ks < 8)
                ? Ap  + (size_t)rg * 512 + ks * 64 + acsw[j] * 8
                : xbf + (size_t)rg * 256 + (ks - 8) * 64 + acsw[j] * 8;
            gload16(s, A_lds(buf) + (size_t)(j * 512 + wbase) * 8);
        }
        #pragma unroll
        for (int j = 0; j < 4; ++j) {
            const unsigned short* s = WcT + (size_t)brow[j] * 768 + ks * 64 + bcsw[j] * 8;
            gload16(s, B_lds(buf) + (size_t)(j * 512 + wbase) * 8);
        }
    };

    f32x4 acc[4][8];
    #pragma unroll
    for (int m = 0; m < 4; m++)
        #pragma unroll
        for (int n = 0; n < 8; n++)
            acc[m][n] = (f32x4){0.f, 0.f, 0.f, 0.f};

    stage(0, 0);

    #pragma unroll
    for (int ks = 0; ks < 12; ++ks) {
        const int buf = ks & 1;
        asm volatile("s_waitcnt vmcnt(0)" ::: "memory");
        __builtin_amdgcn_s_barrier();
        __builtin_amdgcn_sched_barrier(0);
        if (ks + 1 < 12) stage(buf ^ 1, ks + 1);   // overwrites buffer last read at ks-1
        __builtin_amdgcn_sched_barrier(0);
        const unsigned short* Ab = A_lds(buf);
        const unsigned short* Bb = B_lds(buf);
        #pragma unroll
        for (int h = 0; h < 2; ++h) {
            short8 av[4], bv[8];
            #pragma unroll
            for (int m = 0; m < 4; m++)
                av[m] = *(const short8*)&Ab[(size_t)((wm * 64 + m * 16 + lr) * 8 + ((h * 4 + qk) ^ sxr)) * 8];
            #pragma unroll
            for (int n = 0; n < 8; n++)
                bv[n] = *(const short8*)&Bb[(size_t)((wn * 128 + n * 16 + lr) * 8 + ((h * 4 + qk) ^ sxr)) * 8];
            #pragma unroll
            for (int m = 0; m < 4; m++)
                #pragma unroll
                for (int n = 0; n < 8; n++)
                    acc[m][n] = __builtin_amdgcn_mfma_f32_16x16x32_bf16(av[m], bv[n], acc[m][n], 0, 0, 0);
        }
    }
    __syncthreads();   // all waves done with LDS tiles before epilogue reuses smem

    // ---- epilogue: h = acc/3 + bias (bf16), LDS-staged coalesced store, BN partials ----
    unsigned short* Cst = (unsigned short*)smem;     // [64][264] ushort = 33792 B
    float* bs = (float*)(smem + 34816);              // 512 floats
    bs[t] = 0.f;
    __syncthreads();

    const float inv3 = 1.f / 3.f;
    float bco[8];
    #pragma unroll
    for (int n = 0; n < 8; n++) bco[n] = bias[wn * 128 + n * 16 + lr];

    float s[8]  = {0.f, 0.f, 0.f, 0.f, 0.f, 0.f, 0.f, 0.f};
    float s2[8] = {0.f, 0.f, 0.f, 0.f, 0.f, 0.f, 0.f, 0.f};

    #pragma unroll
    for (int p = 0; p < 4; ++p) {
        if (wm == p) {
            #pragma unroll
            for (int m = 0; m < 4; m++) {
                #pragma unroll
                for (int n = 0; n < 8; n++) {
                    const int col = wn * 128 + n * 16 + lr;
                    #pragma unroll
                    for (int j = 0; j < 4; j++) {
                        int rl = m * 16 + qk * 4 + j;
                        float h = acc[m][n][j] * inv3 + bco[n];
                        if (m0 + p * 64 + rl < V_N) { s[n] += h; s2[n] += h * h; }
                        Cst[rl * 264 + col] = f2bf(h);
                    }
                }
            }
        }
        __syncthreads();
        #pragma unroll
        for (int i = 0; i < 4; ++i) {
            int f = t + i * 512;            // 0..2047 chunks of 8 ushorts
            int row = f >> 5;
            int c8  = (f & 31) * 8;
            int r = m0 + p * 64 + row;
            if (r < V_N) {
                uint4 val = *(const uint4*)&Cst[row * 264 + c8];
                *(uint4*)&Ap[(size_t)r * 512 + c8] = val;
            }
        }
        __syncthreads();
    }

    #pragma unroll
    for (int n = 0; n < 8; n++) {
        s[n]  += __shfl_xor(s[n], 16);  s[n]  += __shfl_xor(s[n], 32);
        s2[n] += __shfl_xor(s2[n], 16); s2[n] += __shfl_xor(s2[n], 32);
    }
    if (lane < 16) {
        #pragma unroll
        for (int n = 0; n < 8; n++) {
            const int col = wn * 128 + n * 16 + lr;
            atomicAdd(&bs[col], s[n]);
            atomicAdd(&bs[256 + col], s2[n]);
        }
    }
    __syncthreads();
    partial[(size_t)blockIdx.x * 512 + t] = bs[t];
}

// ---------------- BN reduce + finalize + normalize ----------------

__global__ void bn_reduce_part(const float* __restrict__ partial, float* __restrict__ sums) {
    int t = threadIdx.x;                       // 512
    int b0 = blockIdx.x * BRCHUNK;
    int b1 = b0 + BRCHUNK; if (b1 > MTILES) b1 = MTILES;
    float S = 0.f;
    for (int b = b0; b < b1; b++) S += partial[(size_t)b * 512 + t];
    atomicAdd(&sums[t], S);
}

__global__ void bn_finalize(const float* __restrict__ sums, float* __restrict__ ms) {
    int c = threadIdx.x;                       // 256
    float mean = sums[c] / (float)V_N;
    float var  = sums[256 + c] / (float)V_N - mean * mean;
    ms[c]       = mean;
    ms[256 + c] = rsqrtf(var + BN_EPS);
}

// read h (bf16, Apre rows), write normalized f32 out
__global__ void bn_norm2(const unsigned short* __restrict__ hbf,
                         const float* __restrict__ ms, float* __restrict__ out) {
    const size_t total8 = (size_t)V_N * 32;    // chunks of 8 elems
    size_t stride = (size_t)gridDim.x * blockDim.x;
    for (size_t idx = (size_t)blockIdx.x * blockDim.x + threadIdx.x; idx < total8; idx += stride) {
        size_t v  = idx >> 5;
        int   c8  = (int)(idx & 31) * 8;
        uint4 uv = *(const uint4*)&hbf[v * 512 + c8];
        float4 ma = *(const float4*)&ms[c8];
        float4 mb = *(const float4*)&ms[c8 + 4];
        float4 ra = *(const float4*)&ms[256 + c8];
        float4 rb = *(const float4*)&ms[256 + c8 + 4];
        unsigned int w0 = uv.x, w1 = uv.y, w2 = uv.z, w3 = uv.w;
        float4 h0, h1;
        h0.x = (blo(w0) - ma.x) * ra.x;
        h0.y = (bhi(w0) - ma.y) * ra.y;
        h0.z = (blo(w1) - ma.z) * ra.z;
        h0.w = (bhi(w1) - ma.w) * ra.w;
        h1.x = (blo(w2) - mb.x) * rb.x;
        h1.y = (bhi(w2) - mb.y) * rb.y;
        h1.z = (blo(w3) - mb.z) * rb.z;
        h1.w = (bhi(w3) - mb.w) * rb.w;
        float* o = out + v * 256 + c8;
        *(float4*)o       = h0;
        *(float4*)(o + 4) = h1;
    }
}

__global__ void rel_out_kernel(const float* __restrict__ rel_repr,
                               const float* __restrict__ loop_rel,
                               const float* __restrict__ w_rel,
                               float* __restrict__ out)
{
    int r = blockIdx.x;
    const float* row = (r < NREL2) ? (rel_repr + (size_t)r * IN_C) : loop_rel;
    int l = threadIdx.x;
    float s = 0.f;
    #pragma unroll
    for (int q = 0; q < 4; q++) {
        int k = l + q * 64;
        s += row[k] * w_rel[(size_t)k * OUT_C + (OUT_C - 1)];
    }
    #pragma unroll
    for (int m = 32; m >= 1; m >>= 1) s += __shfl_xor(s, m);
    if (l == 0) out[(size_t)V_N * OUT_C + r] = s;
}

// ---------------- launch ----------------

extern "C" void kernel_launch(void* const* d_in, const int* in_sizes, int n_in,
                              void* d_out, int out_size, void* d_ws, size_t ws_size,
                              hipStream_t stream) {
    const float* x        = (const float*)d_in[0];
    const float* rel_repr = (const float*)d_in[1];
    const float* w        = (const float*)d_in[2];
    const float* w_rel    = (const float*)d_in[3];
    const float* loop_rel = (const float*)d_in[4];
    const float* bias     = (const float*)d_in[5];
    const int*   src      = (const int*)d_in[6];
    const int*   dst      = (const int*)d_in[7];
    const int*   etype    = (const int*)d_in[8];
    const int*   edir     = (const int*)d_in[9];
    float* out = (float*)d_out;
    unsigned short* xbf = (unsigned short*)d_out;   // [V][256] bf16 scratch (dead after GEMM)

    // workspace layout (105.60 MB, within round-2-proven bound)
    char* wsb = (char*)d_ws;
    int*   cnt     = (int*)(wsb + 0);              // 400,000
    int*   cursor  = (int*)(wsb + 400000);         // 400,000 (dead after scatter)
    unsigned short* relbf = (unsigned short*)(wsb + 400000);  // 242,688 (reuses cursor)
    int*   offs    = (int*)(wsb + 800000);         // 400,000
    float* degi    = (float*)(wsb + 1200000);      // 400,000
    int*   bsum    = (int*)(wsb + 1600000);        // 392
    float* partial = (float*)(wsb + 0);            // alias region0 (391*2048 < 1,601,792)
    int*   epack   = (int*)(wsb + 1601792);        // 1,200,000
    float* ms      = (float*)(wsb + 2801792);      // 2048
    float* sums    = (float*)(wsb + 2803840);      // 2048
    unsigned short* WcT  = (unsigned short*)(wsb + 2805888);   // 393,216
    unsigned short* Apre = (unsigned short*)(wsb + 3199104);   // 102,400,000

    hipMemsetAsync(wsb, 0, 800000, stream);        // cnt + cursor
    hipMemsetAsync(sums, 0, 2048, stream);

    count_kernel<<<(E_N + 255) / 256, 256, 0, stream>>>(dst, cnt);
    scan1<<<NB_SCAN, 1024, 0, stream>>>(cnt, bsum, degi);
    scan2<<<1, 128, 0, stream>>>(bsum);
    scan3<<<NB_SCAN, 1024, 0, stream>>>(cnt, bsum, offs);
    scatter_kernel<<<(E_N + 255) / 256, 256, 0, stream>>>(dst, src, etype, edir,
                                                          offs, cursor, epack);
    convert_w<<<768, 256, 0, stream>>>(w, loop_rel, WcT);
    convert_x<<<2048, 256, 0, stream>>>(x, xbf);
    convert_rel<<<(NREL2 * 32 + 255) / 256, 256, 0, stream>>>(rel_repr, relbf);
    aggregate<<<(V_N * 32 + 255) / 256, 256, 0, stream>>>(xbf, relbf, degi, cnt, offs,
                                                          epack, Apre);
    mfma_gemm<<<MTILES, 512, 0, stream>>>(Apre, xbf, WcT, bias, partial);
    bn_reduce_part<<<4, 512, 0, stream>>>(partial, sums);
    bn_finalize<<<1, 256, 0, stream>>>(sums, ms);
    bn_norm2<<<2048, 256, 0, stream>>>(Apre, ms, out);
    rel_out_kernel<<<NREL2 + 1, 64, 0, stream>>>(rel_repr, loop_rel, w_rel, out);
}

// Round 11
// 247.090 us; speedup vs baseline: 1.3819x; 1.0133x over previous
//
#include <hip/hip_runtime.h>

#define V_N   100000
#define E_N   300000
#define IN_C  256
#define OUT_C 256
#define NREL2 474
#define BN_EPS 1e-5f
#define NB_SCAN 98            // ceil(V_N/1024)
#define MTILES 391            // ceil(V_N/256)
#define BRCHUNK 98            // ceil(MTILES/4)

typedef __attribute__((ext_vector_type(8))) short short8;
typedef __attribute__((ext_vector_type(4))) float f32x4;

__device__ __forceinline__ unsigned short f2bf(float f) {
    unsigned int u = __builtin_bit_cast(unsigned int, f);
    u += 0x7FFFu + ((u >> 16) & 1u);          // RNE
    return (unsigned short)(u >> 16);
}
__device__ __forceinline__ unsigned int pk2bf(float lo, float hi) {
    return (unsigned int)f2bf(lo) | ((unsigned int)f2bf(hi) << 16);
}
__device__ __forceinline__ float blo(unsigned int u) {
    return __builtin_bit_cast(float, u << 16);
}
__device__ __forceinline__ float bhi(unsigned int u) {
    return __builtin_bit_cast(float, u & 0xFFFF0000u);
}

typedef const __attribute__((address_space(1))) unsigned int* gas1_t;
typedef __attribute__((address_space(3))) unsigned int* las3_t;
__device__ __forceinline__ void gload16(const void* g, void* l) {
    __builtin_amdgcn_global_load_lds((gas1_t)g, (las3_t)l, 16, 0, 0);
}

// ---------------- CSR build ----------------

__global__ void count_kernel(const int* __restrict__ dst, int* __restrict__ cnt) {
    int e = blockIdx.x * 256 + threadIdx.x;
    if (e < E_N) atomicAdd(&cnt[dst[e]], 1);
}

// coalesced per-block sums; also emits degi = rsqrt(cnt)
__global__ __launch_bounds__(1024)
void scan1(const int* __restrict__ cnt, int* __restrict__ bsum, float* __restrict__ degi) {
    __shared__ int red[1024];
    int t = threadIdx.x;
    int v = blockIdx.x * 1024 + t;
    int c = (v < V_N) ? cnt[v] : 0;
    if (v < V_N) degi[v] = c > 0 ? rsqrtf((float)c) : 0.f;
    red[t] = c;
    __syncthreads();
    for (int s = 512; s > 0; s >>= 1) {
        if (t < s) red[t] += red[t + s];
        __syncthreads();
    }
    if (t == 0) bsum[blockIdx.x] = red[0];
}

// parallel exclusive scan of the 98 block sums (one 128-thread block)
__global__ void scan2(int* bsum) {
    __shared__ int sc[128];
    int t = threadIdx.x;
    int v = (t < NB_SCAN) ? bsum[t] : 0;
    sc[t] = v;
    __syncthreads();
    for (int d = 1; d < 128; d <<= 1) {
        int add = (t >= d) ? sc[t - d] : 0;
        __syncthreads();
        sc[t] += add;
        __syncthreads();
    }
    if (t < NB_SCAN) bsum[t] = sc[t] - v;   // exclusive
}

__global__ __launch_bounds__(1024)
void scan3(const int* __restrict__ cnt, const int* __restrict__ bsum,
           int* __restrict__ offs) {
    __shared__ int sc[1024];
    int t = threadIdx.x;
    int v = blockIdx.x * 1024 + t;
    int c = (v < V_N) ? cnt[v] : 0;
    sc[t] = c;
    __syncthreads();
    for (int d = 1; d < 1024; d <<= 1) {
        int add = (t >= d) ? sc[t - d] : 0;
        __syncthreads();
        sc[t] += add;
        __syncthreads();
    }
    if (v < V_N) offs[v] = sc[t] - c + bsum[blockIdx.x];
}

__global__ void scatter_kernel(const int* __restrict__ dst, const int* __restrict__ src,
                               const int* __restrict__ etype, const int* __restrict__ edir,
                               const int* __restrict__ offs, int* __restrict__ cursor,
                               int* __restrict__ epack) {
    int e = blockIdx.x * 256 + threadIdx.x;
    if (e < E_N) {
        int d = dst[e];
        int pos = offs[d] + atomicAdd(&cursor[d], 1);
        epack[pos] = src[e] | (etype[e] << 17) | (edir[e] << 26);
    }
}

// WcT[n][k] = bf16(w_flat[k][n]); rows k>=512 pre-multiplied by loop_rel[k-512]
__global__ void convert_w(const float* __restrict__ w, const float* __restrict__ loop_rel,
                          unsigned short* __restrict__ WcT) {
    int k = blockIdx.x;    // 0..767
    int n = threadIdx.x;   // 0..255
    float f = w[(size_t)k * 256 + n];
    if (k >= 512) f *= loop_rel[k - 512];
    WcT[(size_t)n * 768 + k] = f2bf(f);
}

// x -> xbf (bf16, plain [V][256], lives in d_out scratch)
__global__ void convert_x(const float* __restrict__ x, unsigned short* __restrict__ xbf) {
    const size_t total8 = (size_t)V_N * 32;    // 8-elem chunks
    size_t stride = (size_t)gridDim.x * blockDim.x;
    for (size_t idx = (size_t)blockIdx.x * blockDim.x + threadIdx.x; idx < total8; idx += stride) {
        const float* s = x + idx * 8;
        float4 a = *(const float4*)s, b = *(const float4*)(s + 4);
        uint4 u;
        u.x = pk2bf(a.x, a.y); u.y = pk2bf(a.z, a.w);
        u.z = pk2bf(b.x, b.y); u.w = pk2bf(b.z, b.w);
        *(uint4*)(xbf + idx * 8) = u;
    }
}

// rel_repr -> relbf (bf16, [NREL2][256])
__global__ void convert_rel(const float* __restrict__ rel, unsigned short* __restrict__ relbf) {
    const int total8 = NREL2 * 32;
    int idx = blockIdx.x * 256 + threadIdx.x;
    if (idx < total8) {
        const float* s = rel + (size_t)idx * 8;
        float4 a = *(const float4*)s, b = *(const float4*)(s + 4);
        uint4 u;
        u.x = pk2bf(a.x, a.y); u.y = pk2bf(a.z, a.w);
        u.z = pk2bf(b.x, b.y); u.w = pk2bf(b.z, b.w);
        *(uint4*)(relbf + (size_t)idx * 8) = u;
    }
}

// ---------------- aggregate: HALF-WAVE (32 lanes) per dst node, bf16 gathers ----------------
// Apre[v][0..255]=dir0 agg, [256..511]=dir1 agg (bf16).
__global__ __launch_bounds__(256)
void aggregate(const unsigned short* __restrict__ xbf,
               const unsigned short* __restrict__ relbf,
               const float* __restrict__ degi,
               const int* __restrict__ cnt, const int* __restrict__ offs,
               const int* __restrict__ epack, unsigned short* __restrict__ Apre) {
    const int node = (blockIdx.x * 256 + threadIdx.x) >> 5;
    const int lane = threadIdx.x & 31;
    if (node >= V_N) return;
    const int v = node;
    const int n = cnt[v];
    const int base = offs[v];
    const float dv = degi[v];
    const int c8 = lane * 8;                 // this lane owns 8 elems of the row

    float a0[8] = {0,0,0,0,0,0,0,0};
    float a1[8] = {0,0,0,0,0,0,0,0};

    int i = 0;
    for (; i + 2 <= n; i += 2) {
        int p0 = epack[base + i];
        int p1 = epack[base + i + 1];
        int s0 = p0 & 0x1FFFF, s1 = p1 & 0x1FFFF;
        int t0 = (p0 >> 17) & 0x1FF, t1 = (p1 >> 17) & 0x1FF;
        float en0 = degi[s0] * dv, en1 = degi[s1] * dv;
        float e00 = (p0 & (1 << 26)) ? 0.f : en0, e01 = en0 - e00;
        float e10 = (p1 & (1 << 26)) ? 0.f : en1, e11 = en1 - e10;
        uint4 xu0 = *(const uint4*)(xbf   + (size_t)s0 * 256 + c8);
        uint4 ru0 = *(const uint4*)(relbf + (size_t)t0 * 256 + c8);
        uint4 xu1 = *(const uint4*)(xbf   + (size_t)s1 * 256 + c8);
        uint4 ru1 = *(const uint4*)(relbf + (size_t)t1 * 256 + c8);
        float m[8];
        m[0] = blo(xu0.x) * blo(ru0.x); m[1] = bhi(xu0.x) * bhi(ru0.x);
        m[2] = blo(xu0.y) * blo(ru0.y); m[3] = bhi(xu0.y) * bhi(ru0.y);
        m[4] = blo(xu0.z) * blo(ru0.z); m[5] = bhi(xu0.z) * bhi(ru0.z);
        m[6] = blo(xu0.w) * blo(ru0.w); m[7] = bhi(xu0.w) * bhi(ru0.w);
        #pragma unroll
        for (int j = 0; j < 8; j++) { a0[j] += m[j] * e00; a1[j] += m[j] * e01; }
        m[0] = blo(xu1.x) * blo(ru1.x); m[1] = bhi(xu1.x) * bhi(ru1.x);
        m[2] = blo(xu1.y) * blo(ru1.y); m[3] = bhi(xu1.y) * bhi(ru1.y);
        m[4] = blo(xu1.z) * blo(ru1.z); m[5] = bhi(xu1.z) * bhi(ru1.z);
        m[6] = blo(xu1.w) * blo(ru1.w); m[7] = bhi(xu1.w) * bhi(ru1.w);
        #pragma unroll
        for (int j = 0; j < 8; j++) { a0[j] += m[j] * e10; a1[j] += m[j] * e11; }
    }
    if (i < n) {
        int p = epack[base + i];
        int s = p & 0x1FFFF;
        int tt = (p >> 17) & 0x1FF;
        float en = degi[s] * dv;
        float e0 = (p & (1 << 26)) ? 0.f : en, e1 = en - e0;
        uint4 xu = *(const uint4*)(xbf   + (size_t)s * 256 + c8);
        uint4 ru = *(const uint4*)(relbf + (size_t)tt * 256 + c8);
        float m[8];
        m[0] = blo(xu.x) * blo(ru.x); m[1] = bhi(xu.x) * bhi(ru.x);
        m[2] = blo(xu.y) * blo(ru.y); m[3] = bhi(xu.y) * bhi(ru.y);
        m[4] = blo(xu.z) * blo(ru.z); m[5] = bhi(xu.z) * bhi(ru.z);
        m[6] = blo(xu.w) * blo(ru.w); m[7] = bhi(xu.w) * bhi(ru.w);
        #pragma unroll
        for (int j = 0; j < 8; j++) { a0[j] += m[j] * e0; a1[j] += m[j] * e1; }
    }

    uint4 u0, u1;
    u0.x = pk2bf(a0[0], a0[1]); u0.y = pk2bf(a0[2], a0[3]);
    u0.z = pk2bf(a0[4], a0[5]); u0.w = pk2bf(a0[6], a0[7]);
    u1.x = pk2bf(a1[0], a1[1]); u1.y = pk2bf(a1[2], a1[3]);
    u1.z = pk2bf(a1[4], a1[5]); u1.w = pk2bf(a1[6], a1[7]);
    *(uint4*)(Apre + (size_t)v * 512 + c8)       = u0;
    *(uint4*)(Apre + (size_t)v * 512 + 256 + c8) = u1;
}

// ---------------- fused GEMM: 256x256 tile, asymmetric pipeline (A 3-deep, B 2-deep) ----------------
// out_h(bf16, into Apre rows) = [Apre | xbf] @ WcT^T, /3 + bias; BN col partials.
// 256x256 per block, 8 waves (4x2), wave tile 64x128 (acc[4][8]). K=768, BK=64, 12 steps.
// LDS: A ring 3x32KB @0 (long-latency L3/HBM stream, 2 compute-phases in flight),
//      B dbuf 2x32KB @98304 (L2-resident WcT, 1 phase) = 160KB total (full pool).
// Per step: vmcnt(4) drains A(ks)+B(ks) keeping A(ks+1); barrier; issue B(ks+1)
// then A(ks+2); compute. Queue at wait is [A(ks), B(ks), A(ks+1)] -> count exact.
__global__ __launch_bounds__(512)
void mfma_gemm(unsigned short* Ap /* Apre, also h output */,
               const unsigned short* __restrict__ xbf,
               const unsigned short* __restrict__ WcT,
               const float* __restrict__ bias, float* __restrict__ partial) {
    __shared__ __align__(16) unsigned char smem[163840];

    const int t    = threadIdx.x;
    const int m0   = blockIdx.x * 256;
    const int wid  = t >> 6;
    const int lane = t & 63;
    const int wm   = wid >> 1;          // 0..3 row-group
    const int wn   = wid & 1;           // 0..1 col-group
    const int lr   = lane & 15;
    const int qk   = lane >> 4;
    const int sxr  = lr & 7;
    const int wbase = t & 0x1C0;

    // staging constants: 2048 chunks each for A and B, 4 per thread
    int arow[4], acsw[4], brow[4], bcsw[4];
    #pragma unroll
    for (int j = 0; j < 4; ++j) {
        int g = j * 512 + t;
        arow[j] = g >> 3;               // 0..255 row
        acsw[j] = (g & 7) ^ (arow[j] & 7);
        brow[j] = g >> 3;               // 0..255 col
        bcsw[j] = (g & 7) ^ (brow[j] & 7);
    }

    auto A_lds = [&](int b3) { return (unsigned short*)(smem + b3 * 32768); };
    auto B_lds = [&](int b2) { return (unsigned short*)(smem + 98304 + b2 * 32768); };

    auto stageA = [&](int buf, int ks) {
        #pragma unroll
        for (int j = 0; j < 4; ++j) {
            int rg = m0 + arow[j];
            if (rg >= V_N) rg = V_N - 1;
            const unsigned short* s = (ks < 8)
                ? Ap  + (size_t)rg * 512 + ks * 64 + acsw[j] * 8
                : xbf + (size_t)rg * 256 + (ks - 8) * 64 + acsw[j] * 8;
            gload16(s, A_lds(buf) + (size_t)(j * 512 + wbase) * 8);
        }
    };
    auto stageB = [&](int buf, int ks) {
        #pragma unroll
        for (int j = 0; j < 4; ++j) {
            const unsigned short* s = WcT + (size_t)brow[j] * 768 + ks * 64 + bcsw[j] * 8;
            gload16(s, B_lds(buf) + (size_t)(j * 512 + wbase) * 8);
        }
    };

    f32x4 acc[4][8];
    #pragma unroll
    for (int m = 0; m < 4; m++)
        #pragma unroll
        for (int n = 0; n < 8; n++)
            acc[m][n] = (f32x4){0.f, 0.f, 0.f, 0.f};

    // prologue: A(0), B(0), A(1)  (issue order matters for vmcnt counting)
    stageA(0, 0);
    stageB(0, 0);
    stageA(1, 1);

    #pragma unroll
    for (int ks = 0; ks < 12; ++ks) {
        const int a3 = ks % 3;
        const int b2 = ks & 1;
        if (ks < 11) { asm volatile("s_waitcnt vmcnt(4)" ::: "memory"); }
        else         { asm volatile("s_waitcnt vmcnt(0)" ::: "memory"); }
        __builtin_amdgcn_s_barrier();
        __builtin_amdgcn_sched_barrier(0);
        if (ks + 1 < 12) stageB((ks + 1) & 1, ks + 1);   // B-buf last read at ks-1
        if (ks + 2 < 12) stageA((ks + 2) % 3, ks + 2);   // A-buf last read at ks-1
        __builtin_amdgcn_sched_barrier(0);
        const unsigned short* Ab = A_lds(a3);
        const unsigned short* Bb = B_lds(b2);
        #pragma unroll
        for (int h = 0; h < 2; ++h) {
            short8 av[4], bv[8];
            #pragma unroll
            for (int m = 0; m < 4; m++)
                av[m] = *(const short8*)&Ab[(size_t)((wm * 64 + m * 16 + lr) * 8 + ((h * 4 + qk) ^ sxr)) * 8];
            #pragma unroll
            for (int n = 0; n < 8; n++)
                bv[n] = *(const short8*)&Bb[(size_t)((wn * 128 + n * 16 + lr) * 8 + ((h * 4 + qk) ^ sxr)) * 8];
            #pragma unroll
            for (int m = 0; m < 4; m++)
                #pragma unroll
                for (int n = 0; n < 8; n++)
                    acc[m][n] = __builtin_amdgcn_mfma_f32_16x16x32_bf16(av[m], bv[n], acc[m][n], 0, 0, 0);
        }
    }
    __syncthreads();   // all waves done with LDS tiles before epilogue reuses smem

    // ---- epilogue: h = acc/3 + bias (bf16), LDS-staged coalesced store, BN partials ----
    unsigned short* Cst = (unsigned short*)smem;     // [64][264] ushort = 33792 B
    float* bs = (float*)(smem + 34816);              // 512 floats
    bs[t] = 0.f;
    __syncthreads();

    const float inv3 = 1.f / 3.f;
    float bco[8];
    #pragma unroll
    for (int n = 0; n < 8; n++) bco[n] = bias[wn * 128 + n * 16 + lr];

    float s[8]  = {0.f, 0.f, 0.f, 0.f, 0.f, 0.f, 0.f, 0.f};
    float s2[8] = {0.f, 0.f, 0.f, 0.f, 0.f, 0.f, 0.f, 0.f};

    #pragma unroll
    for (int p = 0; p < 4; ++p) {
        if (wm == p) {
            #pragma unroll
            for (int m = 0; m < 4; m++) {
                #pragma unroll
                for (int n = 0; n < 8; n++) {
                    const int col = wn * 128 + n * 16 + lr;
                    #pragma unroll
                    for (int j = 0; j < 4; j++) {
                        int rl = m * 16 + qk * 4 + j;
                        float h = acc[m][n][j] * inv3 + bco[n];
                        if (m0 + p * 64 + rl < V_N) { s[n] += h; s2[n] += h * h; }
                        Cst[rl * 264 + col] = f2bf(h);
                    }
                }
            }
        }
        __syncthreads();
        #pragma unroll
        for (int i = 0; i < 4; ++i) {
            int f = t + i * 512;            // 0..2047 chunks of 8 ushorts
            int row = f >> 5;
            int c8  = (f & 31) * 8;
            int r = m0 + p * 64 + row;
            if (r < V_N) {
                uint4 val = *(const uint4*)&Cst[row * 264 + c8];
                *(uint4*)&Ap[(size_t)r * 512 + c8] = val;
            }
        }
        __syncthreads();
    }

    #pragma unroll
    for (int n = 0; n < 8; n++) {
        s[n]  += __shfl_xor(s[n], 16);  s[n]  += __shfl_xor(s[n], 32);
        s2[n] += __shfl_xor(s2[n], 16); s2[n] += __shfl_xor(s2[n], 32);
    }
    if (lane < 16) {
        #pragma unroll
        for (int n = 0; n < 8; n++) {
            const int col = wn * 128 + n * 16 + lr;
            atomicAdd(&bs[col], s[n]);
            atomicAdd(&bs[256 + col], s2[n]);
        }
    }
    __syncthreads();
    partial[(size_t)blockIdx.x * 512 + t] = bs[t];
}

// ---------------- BN reduce + finalize + normalize ----------------

__global__ void bn_reduce_part(const float* __restrict__ partial, float* __restrict__ sums) {
    int t = threadIdx.x;                       // 512
    int b0 = blockIdx.x * BRCHUNK;
    int b1 = b0 + BRCHUNK; if (b1 > MTILES) b1 = MTILES;
    float S = 0.f;
    for (int b = b0; b < b1; b++) S += partial[(size_t)b * 512 + t];
    atomicAdd(&sums[t], S);
}

__global__ void bn_finalize(const float* __restrict__ sums, float* __restrict__ ms) {
    int c = threadIdx.x;                       // 256
    float mean = sums[c] / (float)V_N;
    float var  = sums[256 + c] / (float)V_N - mean * mean;
    ms[c]       = mean;
    ms[256 + c] = rsqrtf(var + BN_EPS);
}

// read h (bf16, Apre rows), write normalized f32 out
__global__ void bn_norm2(const unsigned short* __restrict__ hbf,
                         const float* __restrict__ ms, float* __restrict__ out) {
    const size_t total8 = (size_t)V_N * 32;    // chunks of 8 elems
    size_t stride = (size_t)gridDim.x * blockDim.x;
    for (size_t idx = (size_t)blockIdx.x * blockDim.x + threadIdx.x; idx < total8; idx += stride) {
        size_t v  = idx >> 5;
        int   c8  = (int)(idx & 31) * 8;
        uint4 uv = *(const uint4*)&hbf[v * 512 + c8];
        float4 ma = *(const float4*)&ms[c8];
        float4 mb = *(const float4*)&ms[c8 + 4];
        float4 ra = *(const float4*)&ms[256 + c8];
        float4 rb = *(const float4*)&ms[256 + c8 + 4];
        unsigned int w0 = uv.x, w1 = uv.y, w2 = uv.z, w3 = uv.w;
        float4 h0, h1;
        h0.x = (blo(w0) - ma.x) * ra.x;
        h0.y = (bhi(w0) - ma.y) * ra.y;
        h0.z = (blo(w1) - ma.z) * ra.z;
        h0.w = (bhi(w1) - ma.w) * ra.w;
        h1.x = (blo(w2) - mb.x) * rb.x;
        h1.y = (bhi(w2) - mb.y) * rb.y;
        h1.z = (blo(w3) - mb.z) * rb.z;
        h1.w = (bhi(w3) - mb.w) * rb.w;
        float* o = out + v * 256 + c8;
        *(float4*)o       = h0;
        *(float4*)(o + 4) = h1;
    }
}

__global__ void rel_out_kernel(const float* __restrict__ rel_repr,
                               const float* __restrict__ loop_rel,
                               const float* __restrict__ w_rel,
                               float* __restrict__ out)
{
    int r = blockIdx.x;
    const float* row = (r < NREL2) ? (rel_repr + (size_t)r * IN_C) : loop_rel;
    int l = threadIdx.x;
    float s = 0.f;
    #pragma unroll
    for (int q = 0; q < 4; q++) {
        int k = l + q * 64;
        s += row[k] * w_rel[(size_t)k * OUT_C + (OUT_C - 1)];
    }
    #pragma unroll
    for (int m = 32; m >= 1; m >>= 1) s += __shfl_xor(s, m);
    if (l == 0) out[(size_t)V_N * OUT_C + r] = s;
}

// ---------------- launch ----------------

extern "C" void kernel_launch(void* const* d_in, const int* in_sizes, int n_in,
                              void* d_out, int out_size, void* d_ws, size_t ws_size,
                              hipStream_t stream) {
    const float* x        = (const float*)d_in[0];
    const float* rel_repr = (const float*)d_in[1];
    const float* w        = (const float*)d_in[2];
    const float* w_rel    = (const float*)d_in[3];
    const float* loop_rel = (const float*)d_in[4];
    const float* bias     = (const float*)d_in[5];
    const int*   src      = (const int*)d_in[6];
    const int*   dst      = (const int*)d_in[7];
    const int*   etype    = (const int*)d_in[8];
    const int*   edir     = (const int*)d_in[9];
    float* out = (float*)d_out;
    unsigned short* xbf = (unsigned short*)d_out;   // [V][256] bf16 scratch (dead after GEMM)

    // workspace layout (105.60 MB, within round-2-proven bound)
    char* wsb = (char*)d_ws;
    int*   cnt     = (int*)(wsb + 0);              // 400,000
    int*   cursor  = (int*)(wsb + 400000);         // 400,000 (dead after scatter)
    unsigned short* relbf = (unsigned short*)(wsb + 400000);  // 242,688 (reuses cursor)
    int*   offs    = (int*)(wsb + 800000);         // 400,000
    float* degi    = (float*)(wsb + 1200000);      // 400,000
    int*   bsum    = (int*)(wsb + 1600000);        // 392
    float* partial = (float*)(wsb + 0);            // alias region0 (391*2048 < 1,601,792)
    int*   epack   = (int*)(wsb + 1601792);        // 1,200,000
    float* ms      = (float*)(wsb + 2801792);      // 2048
    float* sums    = (float*)(wsb + 2803840);      // 2048
    unsigned short* WcT  = (unsigned short*)(wsb + 2805888);   // 393,216
    unsigned short* Apre = (unsigned short*)(wsb + 3199104);   // 102,400,000

    hipMemsetAsync(wsb, 0, 800000, stream);        // cnt + cursor
    hipMemsetAsync(sums, 0, 2048, stream);

    count_kernel<<<(E_N + 255) / 256, 256, 0, stream>>>(dst, cnt);
    scan1<<<NB_SCAN, 1024, 0, stream>>>(cnt, bsum, degi);
    scan2<<<1, 128, 0, stream>>>(bsum);
    scan3<<<NB_SCAN, 1024, 0, stream>>>(cnt, bsum, offs);
    scatter_kernel<<<(E_N + 255) / 256, 256, 0, stream>>>(dst, src, etype, edir,
                                                          offs, cursor, epack);
    convert_w<<<768, 256, 0, stream>>>(w, loop_rel, WcT);
    convert_x<<<2048, 256, 0, stream>>>(x, xbf);
    convert_rel<<<(NREL2 * 32 + 255) / 256, 256, 0, stream>>>(rel_repr, relbf);
    aggregate<<<(V_N * 32 + 255) / 256, 256, 0, stream>>>(xbf, relbf, degi, cnt, offs,
                                                          epack, Apre);
    mfma_gemm<<<MTILES, 512, 0, stream>>>(Apre, xbf, WcT, bias, partial);
    bn_reduce_part<<<4, 512, 0, stream>>>(partial, sums);
    bn_finalize<<<1, 256, 0, stream>>>(sums, ms);
    bn_norm2<<<2048, 256, 0, stream>>>(Apre, ms, out);
    rel_out_kernel<<<NREL2 + 1, 64, 0, stream>>>(rel_repr, loop_rel, w_rel, out);
}

// Round 12
// 228.314 us; speedup vs baseline: 1.4956x; 1.0822x over previous
//
#include <hip/hip_runtime.h>

#define V_N   100000
#define E_N   300000
#define IN_C  256
#define OUT_C 256
#define NREL2 474
#define BN_EPS 1e-5f
#define NB_SCAN 98            // ceil(V_N/1024)
#define MTILES 391            // ceil(V_N/256)
#define BRCHUNK 98            // ceil(MTILES/4)
#define CNT_BLKS 1172         // ceil(E_N/256)
#define CVX_BLKS 2048         // convert_x blocks inside count_convx

typedef __attribute__((ext_vector_type(8))) short short8;
typedef __attribute__((ext_vector_type(4))) float f32x4;

__device__ __forceinline__ unsigned short f2bf(float f) {
    unsigned int u = __builtin_bit_cast(unsigned int, f);
    u += 0x7FFFu + ((u >> 16) & 1u);          // RNE
    return (unsigned short)(u >> 16);
}
__device__ __forceinline__ unsigned int pk2bf(float lo, float hi) {
    return (unsigned int)f2bf(lo) | ((unsigned int)f2bf(hi) << 16);
}
__device__ __forceinline__ float blo(unsigned int u) {
    return __builtin_bit_cast(float, u << 16);
}
__device__ __forceinline__ float bhi(unsigned int u) {
    return __builtin_bit_cast(float, u & 0xFFFF0000u);
}

typedef const __attribute__((address_space(1))) unsigned int* gas1_t;
typedef __attribute__((address_space(3))) unsigned int* las3_t;
__device__ __forceinline__ void gload16(const void* g, void* l) {
    __builtin_amdgcn_global_load_lds((gas1_t)g, (las3_t)l, 16, 0, 0);
}

// ---------------- fused: degree count + x->bf16 convert (independent work) ----------------

__global__ void count_convx(const int* __restrict__ dst, int* __restrict__ cnt,
                            const float* __restrict__ x, unsigned short* __restrict__ xbf) {
    if (blockIdx.x < CNT_BLKS) {
        int e = blockIdx.x * 256 + threadIdx.x;
        if (e < E_N) atomicAdd(&cnt[dst[e]], 1);
    } else {
        const size_t total8 = (size_t)V_N * 32;    // 8-elem chunks
        const size_t stride = (size_t)CVX_BLKS * 256;
        for (size_t idx = (size_t)(blockIdx.x - CNT_BLKS) * 256 + threadIdx.x;
             idx < total8; idx += stride) {
            const float* s = x + idx * 8;
            float4 a = *(const float4*)s, b = *(const float4*)(s + 4);
            uint4 u;
            u.x = pk2bf(a.x, a.y); u.y = pk2bf(a.z, a.w);
            u.z = pk2bf(b.x, b.y); u.w = pk2bf(b.z, b.w);
            *(uint4*)(xbf + idx * 8) = u;
        }
    }
}

// ---------------- fused: scan1 + convert_w + convert_rel (independent work) ----------------
// blocks [0,98): per-block cnt sums + degi; [98,290): WcT; [290,305): relbf.

__global__ __launch_bounds__(1024)
void scan1_conv(const int* __restrict__ cnt, int* __restrict__ bsum, float* __restrict__ degi,
                const float* __restrict__ w, const float* __restrict__ loop_rel,
                unsigned short* __restrict__ WcT,
                const float* __restrict__ rel, unsigned short* __restrict__ relbf) {
    const int bid = blockIdx.x;
    const int t = threadIdx.x;
    if (bid < NB_SCAN) {
        __shared__ int red[1024];
        int v = bid * 1024 + t;
        int c = (v < V_N) ? cnt[v] : 0;
        if (v < V_N) degi[v] = c > 0 ? rsqrtf((float)c) : 0.f;
        red[t] = c;
        __syncthreads();
        for (int s = 512; s > 0; s >>= 1) {
            if (t < s) red[t] += red[t + s];
            __syncthreads();
        }
        if (t == 0) bsum[bid] = red[0];
    } else if (bid < NB_SCAN + 192) {
        int gid = (bid - NB_SCAN) * 1024 + t;      // 0..196607
        int k = gid >> 8;                          // 0..767
        int n = gid & 255;
        float f = w[(size_t)k * 256 + n];
        if (k >= 512) f *= loop_rel[k - 512];
        WcT[(size_t)n * 768 + k] = f2bf(f);
    } else {
        int idx = (bid - NB_SCAN - 192) * 1024 + t;
        if (idx < NREL2 * 32) {
            const float* s = rel + (size_t)idx * 8;
            float4 a = *(const float4*)s, b = *(const float4*)(s + 4);
            uint4 u;
            u.x = pk2bf(a.x, a.y); u.y = pk2bf(a.z, a.w);
            u.z = pk2bf(b.x, b.y); u.w = pk2bf(b.z, b.w);
            *(uint4*)(relbf + (size_t)idx * 8) = u;
        }
    }
}

// ---------------- scan3b: local re-scan of bsum + per-element exclusive scan ----------------

__global__ __launch_bounds__(1024)
void scan3b(const int* __restrict__ cnt, const int* __restrict__ bsum,
            int* __restrict__ offs) {
    __shared__ int sc[1024];
    __shared__ int s2[128];
    __shared__ int s2o[128];
    __shared__ int sbase;
    int t = threadIdx.x;
    if (t < 128) {
        int v = (t < NB_SCAN) ? bsum[t] : 0;
        s2[t] = v; s2o[t] = v;
    }
    __syncthreads();
    for (int d = 1; d < 128; d <<= 1) {
        int add = (t < 128 && t >= d) ? s2[t - d] : 0;
        __syncthreads();
        if (t < 128) s2[t] += add;
        __syncthreads();
    }
    if (t == 0) sbase = s2[blockIdx.x] - s2o[blockIdx.x];   // exclusive prefix for this block
    int v = blockIdx.x * 1024 + t;
    int c = (v < V_N) ? cnt[v] : 0;
    sc[t] = c;
    __syncthreads();                                         // publishes sbase too
    for (int d = 1; d < 1024; d <<= 1) {
        int add = (t >= d) ? sc[t - d] : 0;
        __syncthreads();
        sc[t] += add;
        __syncthreads();
    }
    if (v < V_N) offs[v] = sc[t] - c + sbase;
}

__global__ void scatter_kernel(const int* __restrict__ dst, const int* __restrict__ src,
                               const int* __restrict__ etype, const int* __restrict__ edir,
                               const int* __restrict__ offs, int* __restrict__ cursor,
                               int* __restrict__ epack) {
    int e = blockIdx.x * 256 + threadIdx.x;
    if (e < E_N) {
        int d = dst[e];
        int pos = offs[d] + atomicAdd(&cursor[d], 1);
        epack[pos] = src[e] | (etype[e] << 17) | (edir[e] << 26);
    }
}

// ---------------- aggregate: HALF-WAVE (32 lanes) per dst node, bf16 gathers ----------------
// Apre[v][0..255]=dir0 agg, [256..511]=dir1 agg (bf16).
__global__ __launch_bounds__(256)
void aggregate(const unsigned short* __restrict__ xbf,
               const unsigned short* __restrict__ relbf,
               const float* __restrict__ degi,
               const int* __restrict__ cnt, const int* __restrict__ offs,
               const int* __restrict__ epack, unsigned short* __restrict__ Apre) {
    const int node = (blockIdx.x * 256 + threadIdx.x) >> 5;
    const int lane = threadIdx.x & 31;
    if (node >= V_N) return;
    const int v = node;
    const int n = cnt[v];
    const int base = offs[v];
    const float dv = degi[v];
    const int c8 = lane * 8;                 // this lane owns 8 elems of the row

    float a0[8] = {0,0,0,0,0,0,0,0};
    float a1[8] = {0,0,0,0,0,0,0,0};

    int i = 0;
    for (; i + 2 <= n; i += 2) {
        int p0 = epack[base + i];
        int p1 = epack[base + i + 1];
        int s0 = p0 & 0x1FFFF, s1 = p1 & 0x1FFFF;
        int t0 = (p0 >> 17) & 0x1FF, t1 = (p1 >> 17) & 0x1FF;
        float en0 = degi[s0] * dv, en1 = degi[s1] * dv;
        float e00 = (p0 & (1 << 26)) ? 0.f : en0, e01 = en0 - e00;
        float e10 = (p1 & (1 << 26)) ? 0.f : en1, e11 = en1 - e10;
        uint4 xu0 = *(const uint4*)(xbf   + (size_t)s0 * 256 + c8);
        uint4 ru0 = *(const uint4*)(relbf + (size_t)t0 * 256 + c8);
        uint4 xu1 = *(const uint4*)(xbf   + (size_t)s1 * 256 + c8);
        uint4 ru1 = *(const uint4*)(relbf + (size_t)t1 * 256 + c8);
        float m[8];
        m[0] = blo(xu0.x) * blo(ru0.x); m[1] = bhi(xu0.x) * bhi(ru0.x);
        m[2] = blo(xu0.y) * blo(ru0.y); m[3] = bhi(xu0.y) * bhi(ru0.y);
        m[4] = blo(xu0.z) * blo(ru0.z); m[5] = bhi(xu0.z) * bhi(ru0.z);
        m[6] = blo(xu0.w) * blo(ru0.w); m[7] = bhi(xu0.w) * bhi(ru0.w);
        #pragma unroll
        for (int j = 0; j < 8; j++) { a0[j] += m[j] * e00; a1[j] += m[j] * e01; }
        m[0] = blo(xu1.x) * blo(ru1.x); m[1] = bhi(xu1.x) * bhi(ru1.x);
        m[2] = blo(xu1.y) * blo(ru1.y); m[3] = bhi(xu1.y) * bhi(ru1.y);
        m[4] = blo(xu1.z) * blo(ru1.z); m[5] = bhi(xu1.z) * bhi(ru1.z);
        m[6] = blo(xu1.w) * blo(ru1.w); m[7] = bhi(xu1.w) * bhi(ru1.w);
        #pragma unroll
        for (int j = 0; j < 8; j++) { a0[j] += m[j] * e10; a1[j] += m[j] * e11; }
    }
    if (i < n) {
        int p = epack[base + i];
        int s = p & 0x1FFFF;
        int tt = (p >> 17) & 0x1FF;
        float en = degi[s] * dv;
        float e0 = (p & (1 << 26)) ? 0.f : en, e1 = en - e0;
        uint4 xu = *(const uint4*)(xbf   + (size_t)s * 256 + c8);
        uint4 ru = *(const uint4*)(relbf + (size_t)tt * 256 + c8);
        float m[8];
        m[0] = blo(xu.x) * blo(ru.x); m[1] = bhi(xu.x) * bhi(ru.x);
        m[2] = blo(xu.y) * blo(ru.y); m[3] = bhi(xu.y) * bhi(ru.y);
        m[4] = blo(xu.z) * blo(ru.z); m[5] = bhi(xu.z) * bhi(ru.z);
        m[6] = blo(xu.w) * blo(ru.w); m[7] = bhi(xu.w) * bhi(ru.w);
        #pragma unroll
        for (int j = 0; j < 8; j++) { a0[j] += m[j] * e0; a1[j] += m[j] * e1; }
    }

    uint4 u0, u1;
    u0.x = pk2bf(a0[0], a0[1]); u0.y = pk2bf(a0[2], a0[3]);
    u0.z = pk2bf(a0[4], a0[5]); u0.w = pk2bf(a0[6], a0[7]);
    u1.x = pk2bf(a1[0], a1[1]); u1.y = pk2bf(a1[2], a1[3]);
    u1.z = pk2bf(a1[4], a1[5]); u1.w = pk2bf(a1[6], a1[7]);
    *(uint4*)(Apre + (size_t)v * 512 + c8)       = u0;
    *(uint4*)(Apre + (size_t)v * 512 + 256 + c8) = u1;
}

// ---------------- fused GEMM: 256x256 tile, asymmetric pipeline (A 3-deep, B 2-deep) ----------------
// Main loop identical to round-11 (proven). Epilogue: 2 phases of 128 rows.
__global__ __launch_bounds__(512)
void mfma_gemm(unsigned short* Ap /* Apre, also h output */,
               const unsigned short* __restrict__ xbf,
               const unsigned short* __restrict__ WcT,
               const float* __restrict__ bias, float* __restrict__ partial) {
    __shared__ __align__(16) unsigned char smem[163840];

    const int t    = threadIdx.x;
    const int m0   = blockIdx.x * 256;
    const int wid  = t >> 6;
    const int lane = t & 63;
    const int wm   = wid >> 1;          // 0..3 row-group
    const int wn   = wid & 1;           // 0..1 col-group
    const int lr   = lane & 15;
    const int qk   = lane >> 4;
    const int sxr  = lr & 7;
    const int wbase = t & 0x1C0;

    int arow[4], acsw[4], brow[4], bcsw[4];
    #pragma unroll
    for (int j = 0; j < 4; ++j) {
        int g = j * 512 + t;
        arow[j] = g >> 3;
        acsw[j] = (g & 7) ^ (arow[j] & 7);
        brow[j] = g >> 3;
        bcsw[j] = (g & 7) ^ (brow[j] & 7);
    }

    auto A_lds = [&](int b3) { return (unsigned short*)(smem + b3 * 32768); };
    auto B_lds = [&](int b2) { return (unsigned short*)(smem + 98304 + b2 * 32768); };

    auto stageA = [&](int buf, int ks) {
        #pragma unroll
        for (int j = 0; j < 4; ++j) {
            int rg = m0 + arow[j];
            if (rg >= V_N) rg = V_N - 1;
            const unsigned short* s = (ks < 8)
                ? Ap  + (size_t)rg * 512 + ks * 64 + acsw[j] * 8
                : xbf + (size_t)rg * 256 + (ks - 8) * 64 + acsw[j] * 8;
            gload16(s, A_lds(buf) + (size_t)(j * 512 + wbase) * 8);
        }
    };
    auto stageB = [&](int buf, int ks) {
        #pragma unroll
        for (int j = 0; j < 4; ++j) {
            const unsigned short* s = WcT + (size_t)brow[j] * 768 + ks * 64 + bcsw[j] * 8;
            gload16(s, B_lds(buf) + (size_t)(j * 512 + wbase) * 8);
        }
    };

    f32x4 acc[4][8];
    #pragma unroll
    for (int m = 0; m < 4; m++)
        #pragma unroll
        for (int n = 0; n < 8; n++)
            acc[m][n] = (f32x4){0.f, 0.f, 0.f, 0.f};

    // prologue: A(0), B(0), A(1)
    stageA(0, 0);
    stageB(0, 0);
    stageA(1, 1);

    #pragma unroll
    for (int ks = 0; ks < 12; ++ks) {
        const int a3 = ks % 3;
        const int b2 = ks & 1;
        if (ks < 11) { asm volatile("s_waitcnt vmcnt(4)" ::: "memory"); }
        else         { asm volatile("s_waitcnt vmcnt(0)" ::: "memory"); }
        __builtin_amdgcn_s_barrier();
        __builtin_amdgcn_sched_barrier(0);
        if (ks + 1 < 12) stageB((ks + 1) & 1, ks + 1);
        if (ks + 2 < 12) stageA((ks + 2) % 3, ks + 2);
        __builtin_amdgcn_sched_barrier(0);
        const unsigned short* Ab = A_lds(a3);
        const unsigned short* Bb = B_lds(b2);
        #pragma unroll
        for (int h = 0; h < 2; ++h) {
            short8 av[4], bv[8];
            #pragma unroll
            for (int m = 0; m < 4; m++)
                av[m] = *(const short8*)&Ab[(size_t)((wm * 64 + m * 16 + lr) * 8 + ((h * 4 + qk) ^ sxr)) * 8];
            #pragma unroll
            for (int n = 0; n < 8; n++)
                bv[n] = *(const short8*)&Bb[(size_t)((wn * 128 + n * 16 + lr) * 8 + ((h * 4 + qk) ^ sxr)) * 8];
            #pragma unroll
            for (int m = 0; m < 4; m++)
                #pragma unroll
                for (int n = 0; n < 8; n++)
                    acc[m][n] = __builtin_amdgcn_mfma_f32_16x16x32_bf16(av[m], bv[n], acc[m][n], 0, 0, 0);
        }
    }
    __syncthreads();

    // ---- epilogue: 2 phases of 128 rows; h = acc/3 + bias (bf16); BN col partials ----
    unsigned short* Cst = (unsigned short*)smem;     // [128][264] ushort = 67584 B
    float* bs = (float*)(smem + 67584);              // 512 floats
    bs[t] = 0.f;
    __syncthreads();

    const float inv3 = 1.f / 3.f;
    float bco[8];
    #pragma unroll
    for (int n = 0; n < 8; n++) bco[n] = bias[wn * 128 + n * 16 + lr];

    float s[8]  = {0.f, 0.f, 0.f, 0.f, 0.f, 0.f, 0.f, 0.f};
    float s2[8] = {0.f, 0.f, 0.f, 0.f, 0.f, 0.f, 0.f, 0.f};

    #pragma unroll
    for (int p = 0; p < 2; ++p) {
        if ((wm >> 1) == p) {
            const int rbase = (wm & 1) * 64;
            #pragma unroll
            for (int m = 0; m < 4; m++) {
                #pragma unroll
                for (int n = 0; n < 8; n++) {
                    const int col = wn * 128 + n * 16 + lr;
                    #pragma unroll
                    for (int j = 0; j < 4; j++) {
                        int rl = rbase + m * 16 + qk * 4 + j;
                        float h = acc[m][n][j] * inv3 + bco[n];
                        if (m0 + p * 128 + rl < V_N) { s[n] += h; s2[n] += h * h; }
                        Cst[rl * 264 + col] = f2bf(h);
                    }
                }
            }
        }
        __syncthreads();
        #pragma unroll
        for (int i = 0; i < 8; ++i) {
            int f = t + i * 512;            // 0..4095 chunks of 8 ushorts
            int row = f >> 5;               // 0..127
            int c8  = (f & 31) * 8;
            int r = m0 + p * 128 + row;
            if (r < V_N) {
                uint4 val = *(const uint4*)&Cst[row * 264 + c8];
                *(uint4*)&Ap[(size_t)r * 512 + c8] = val;
            }
        }
        __syncthreads();
    }

    #pragma unroll
    for (int n = 0; n < 8; n++) {
        s[n]  += __shfl_xor(s[n], 16);  s[n]  += __shfl_xor(s[n], 32);
        s2[n] += __shfl_xor(s2[n], 16); s2[n] += __shfl_xor(s2[n], 32);
    }
    if (lane < 16) {
        #pragma unroll
        for (int n = 0; n < 8; n++) {
            const int col = wn * 128 + n * 16 + lr;
            atomicAdd(&bs[col], s[n]);
            atomicAdd(&bs[256 + col], s2[n]);
        }
    }
    __syncthreads();
    partial[(size_t)blockIdx.x * 512 + t] = bs[t];
}

// ---------------- BN reduce + fused finalize+normalize ----------------

__global__ void bn_reduce_part(const float* __restrict__ partial, float* __restrict__ sums) {
    int t = threadIdx.x;                       // 512
    int b0 = blockIdx.x * BRCHUNK;
    int b1 = b0 + BRCHUNK; if (b1 > MTILES) b1 = MTILES;
    float S = 0.f;
    for (int b = b0; b < b1; b++) S += partial[(size_t)b * 512 + t];
    atomicAdd(&sums[t], S);
}

// reads h (bf16, Apre rows), computes mean/rvar per block from sums, writes f32 out
__global__ __launch_bounds__(256)
void bn_norm2f(const unsigned short* __restrict__ hbf, const float* __restrict__ sums,
               float* __restrict__ out) {
    __shared__ float msm[256], msr[256];
    int tt = threadIdx.x;                      // 256
    {
        float mean = sums[tt] * (1.0f / V_N);
        float var  = sums[256 + tt] * (1.0f / V_N) - mean * mean;
        msm[tt] = mean;
        msr[tt] = rsqrtf(var + BN_EPS);
    }
    __syncthreads();
    const size_t total8 = (size_t)V_N * 32;    // chunks of 8 elems
    size_t stride = (size_t)gridDim.x * blockDim.x;
    for (size_t idx = (size_t)blockIdx.x * blockDim.x + tt; idx < total8; idx += stride) {
        size_t v  = idx >> 5;
        int   c8  = (int)(idx & 31) * 8;
        uint4 uv = *(const uint4*)&hbf[v * 512 + c8];
        unsigned int w0 = uv.x, w1 = uv.y, w2 = uv.z, w3 = uv.w;
        float4 h0, h1;
        h0.x = (blo(w0) - msm[c8 + 0]) * msr[c8 + 0];
        h0.y = (bhi(w0) - msm[c8 + 1]) * msr[c8 + 1];
        h0.z = (blo(w1) - msm[c8 + 2]) * msr[c8 + 2];
        h0.w = (bhi(w1) - msm[c8 + 3]) * msr[c8 + 3];
        h1.x = (blo(w2) - msm[c8 + 4]) * msr[c8 + 4];
        h1.y = (bhi(w2) - msm[c8 + 5]) * msr[c8 + 5];
        h1.z = (blo(w3) - msm[c8 + 6]) * msr[c8 + 6];
        h1.w = (bhi(w3) - msm[c8 + 7]) * msr[c8 + 7];
        float* o = out + v * 256 + c8;
        *(float4*)o       = h0;
        *(float4*)(o + 4) = h1;
    }
}

__global__ void rel_out_kernel(const float* __restrict__ rel_repr,
                               const float* __restrict__ loop_rel,
                               const float* __restrict__ w_rel,
                               float* __restrict__ out)
{
    int r = blockIdx.x;
    const float* row = (r < NREL2) ? (rel_repr + (size_t)r * IN_C) : loop_rel;
    int l = threadIdx.x;
    float s = 0.f;
    #pragma unroll
    for (int q = 0; q < 4; q++) {
        int k = l + q * 64;
        s += row[k] * w_rel[(size_t)k * OUT_C + (OUT_C - 1)];
    }
    #pragma unroll
    for (int m = 32; m >= 1; m >>= 1) s += __shfl_xor(s, m);
    if (l == 0) out[(size_t)V_N * OUT_C + r] = s;
}

// ---------------- launch ----------------

extern "C" void kernel_launch(void* const* d_in, const int* in_sizes, int n_in,
                              void* d_out, int out_size, void* d_ws, size_t ws_size,
                              hipStream_t stream) {
    const float* x        = (const float*)d_in[0];
    const float* rel_repr = (const float*)d_in[1];
    const float* w        = (const float*)d_in[2];
    const float* w_rel    = (const float*)d_in[3];
    const float* loop_rel = (const float*)d_in[4];
    const float* bias     = (const float*)d_in[5];
    const int*   src      = (const int*)d_in[6];
    const int*   dst      = (const int*)d_in[7];
    const int*   etype    = (const int*)d_in[8];
    const int*   edir     = (const int*)d_in[9];
    float* out = (float*)d_out;
    unsigned short* xbf   = (unsigned short*)d_out;                      // [V][256] bf16
    unsigned short* relbf = (unsigned short*)((char*)d_out + 51200000);  // [NREL2][256] bf16
    // both dead before bn_norm2f overwrites d_out with f32 output

    // workspace layout (105.60 MB, within round-2-proven bound)
    char* wsb = (char*)d_ws;
    int*   cnt     = (int*)(wsb + 0);              // 400,000
    int*   cursor  = (int*)(wsb + 400000);         // 400,000
    int*   offs    = (int*)(wsb + 800000);         // 400,000
    float* degi    = (float*)(wsb + 1200000);      // 400,000
    int*   bsum    = (int*)(wsb + 1600000);        // 392
    float* partial = (float*)(wsb + 0);            // alias region0 (391*2048 < 1,601,792)
    int*   epack   = (int*)(wsb + 1601792);        // 1,200,000
    float* sums    = (float*)(wsb + 2803840);      // 2048
    unsigned short* WcT  = (unsigned short*)(wsb + 2805888);   // 393,216
    unsigned short* Apre = (unsigned short*)(wsb + 3199104);   // 102,400,000

    hipMemsetAsync(wsb, 0, 800000, stream);        // cnt + cursor
    hipMemsetAsync(sums, 0, 2048, stream);

    count_convx<<<CNT_BLKS + CVX_BLKS, 256, 0, stream>>>(dst, cnt, x, xbf);
    scan1_conv<<<NB_SCAN + 192 + 15, 1024, 0, stream>>>(cnt, bsum, degi,
                                                        w, loop_rel, WcT,
                                                        rel_repr, relbf);
    scan3b<<<NB_SCAN, 1024, 0, stream>>>(cnt, bsum, offs);
    scatter_kernel<<<CNT_BLKS, 256, 0, stream>>>(dst, src, etype, edir,
                                                 offs, cursor, epack);
    aggregate<<<(V_N * 32 + 255) / 256, 256, 0, stream>>>(xbf, relbf, degi, cnt, offs,
                                                          epack, Apre);
    mfma_gemm<<<MTILES, 512, 0, stream>>>(Apre, xbf, WcT, bias, partial);
    bn_reduce_part<<<4, 512, 0, stream>>>(partial, sums);
    bn_norm2f<<<2048, 256, 0, stream>>>(Apre, sums, out);
    rel_out_kernel<<<NREL2 + 1, 64, 0, stream>>>(rel_repr, loop_rel, w_rel, out);
}

// Round 13
// 206.064 us; speedup vs baseline: 1.6570x; 1.1080x over previous
//
#include <hip/hip_runtime.h>

#define V_N   100000
#define E_N   300000
#define IN_C  256
#define OUT_C 256
#define NREL2 474
#define BN_EPS 1e-5f
#define NB_SCAN 98            // ceil(V_N/1024)
#define MTILES 391            // ceil(V_N/256)
#define CNT_BLKS 1172         // ceil(E_N/256)
#define CVX_BLKS 2048         // convert_x blocks inside count_convx
#define BN_BLKS 2048          // bn_norm2f norm-part blocks
#define REL_BLKS 119          // ceil(475/4) rel_out rows, 4 per block

typedef __attribute__((ext_vector_type(8))) short short8;
typedef __attribute__((ext_vector_type(4))) float f32x4;

__device__ __forceinline__ unsigned short f2bf(float f) {
    unsigned int u = __builtin_bit_cast(unsigned int, f);
    u += 0x7FFFu + ((u >> 16) & 1u);          // RNE
    return (unsigned short)(u >> 16);
}
__device__ __forceinline__ unsigned int pk2bf(float lo, float hi) {
    return (unsigned int)f2bf(lo) | ((unsigned int)f2bf(hi) << 16);
}
__device__ __forceinline__ float blo(unsigned int u) {
    return __builtin_bit_cast(float, u << 16);
}
__device__ __forceinline__ float bhi(unsigned int u) {
    return __builtin_bit_cast(float, u & 0xFFFF0000u);
}

typedef const __attribute__((address_space(1))) unsigned int* gas1_t;
typedef __attribute__((address_space(3))) unsigned int* las3_t;
__device__ __forceinline__ void gload16(const void* g, void* l) {
    __builtin_amdgcn_global_load_lds((gas1_t)g, (las3_t)l, 16, 0, 0);
}

// ---------------- fused: degree count + x->bf16 convert (independent work) ----------------

__global__ void count_convx(const int* __restrict__ dst, int* __restrict__ cnt,
                            const float* __restrict__ x, unsigned short* __restrict__ xbf) {
    if (blockIdx.x < CNT_BLKS) {
        int e = blockIdx.x * 256 + threadIdx.x;
        if (e < E_N) atomicAdd(&cnt[dst[e]], 1);
    } else {
        const size_t total8 = (size_t)V_N * 32;    // 8-elem chunks
        const size_t stride = (size_t)CVX_BLKS * 256;
        for (size_t idx = (size_t)(blockIdx.x - CNT_BLKS) * 256 + threadIdx.x;
             idx < total8; idx += stride) {
            const float* s = x + idx * 8;
            float4 a = *(const float4*)s, b = *(const float4*)(s + 4);
            uint4 u;
            u.x = pk2bf(a.x, a.y); u.y = pk2bf(a.z, a.w);
            u.z = pk2bf(b.x, b.y); u.w = pk2bf(b.z, b.w);
            *(uint4*)(xbf + idx * 8) = u;
        }
    }
}

// ---------------- fused: scan1 + convert_w + convert_rel (independent work) ----------------
// blocks [0,98): per-block cnt sums + degi; [98,290): WcT; [290,305): relbf.

__global__ __launch_bounds__(1024)
void scan1_conv(const int* __restrict__ cnt, int* __restrict__ bsum, float* __restrict__ degi,
                const float* __restrict__ w, const float* __restrict__ loop_rel,
                unsigned short* __restrict__ WcT,
                const float* __restrict__ rel, unsigned short* __restrict__ relbf) {
    const int bid = blockIdx.x;
    const int t = threadIdx.x;
    if (bid < NB_SCAN) {
        __shared__ int red[1024];
        int v = bid * 1024 + t;
        int c = (v < V_N) ? cnt[v] : 0;
        if (v < V_N) degi[v] = c > 0 ? rsqrtf((float)c) : 0.f;
        red[t] = c;
        __syncthreads();
        for (int s = 512; s > 0; s >>= 1) {
            if (t < s) red[t] += red[t + s];
            __syncthreads();
        }
        if (t == 0) bsum[bid] = red[0];
    } else if (bid < NB_SCAN + 192) {
        int gid = (bid - NB_SCAN) * 1024 + t;      // 0..196607
        int k = gid >> 8;                          // 0..767
        int n = gid & 255;
        float f = w[(size_t)k * 256 + n];
        if (k >= 512) f *= loop_rel[k - 512];
        WcT[(size_t)n * 768 + k] = f2bf(f);
    } else {
        int idx = (bid - NB_SCAN - 192) * 1024 + t;
        if (idx < NREL2 * 32) {
            const float* s = rel + (size_t)idx * 8;
            float4 a = *(const float4*)s, b = *(const float4*)(s + 4);
            uint4 u;
            u.x = pk2bf(a.x, a.y); u.y = pk2bf(a.z, a.w);
            u.z = pk2bf(b.x, b.y); u.w = pk2bf(b.z, b.w);
            *(uint4*)(relbf + (size_t)idx * 8) = u;
        }
    }
}

// ---------------- scan3b: local re-scan of bsum + per-element exclusive scan ----------------

__global__ __launch_bounds__(1024)
void scan3b(const int* __restrict__ cnt, const int* __restrict__ bsum,
            int* __restrict__ offs) {
    __shared__ int sc[1024];
    __shared__ int s2[128];
    __shared__ int s2o[128];
    __shared__ int sbase;
    int t = threadIdx.x;
    if (t < 128) {
        int v = (t < NB_SCAN) ? bsum[t] : 0;
        s2[t] = v; s2o[t] = v;
    }
    __syncthreads();
    for (int d = 1; d < 128; d <<= 1) {
        int add = (t < 128 && t >= d) ? s2[t - d] : 0;
        __syncthreads();
        if (t < 128) s2[t] += add;
        __syncthreads();
    }
    if (t == 0) sbase = s2[blockIdx.x] - s2o[blockIdx.x];   // exclusive prefix for this block
    int v = blockIdx.x * 1024 + t;
    int c = (v < V_N) ? cnt[v] : 0;
    sc[t] = c;
    __syncthreads();                                         // publishes sbase too
    for (int d = 1; d < 1024; d <<= 1) {
        int add = (t >= d) ? sc[t - d] : 0;
        __syncthreads();
        sc[t] += add;
        __syncthreads();
    }
    if (v < V_N) offs[v] = sc[t] - c + sbase;
}

__global__ void scatter_kernel(const int* __restrict__ dst, const int* __restrict__ src,
                               const int* __restrict__ etype, const int* __restrict__ edir,
                               const int* __restrict__ offs, int* __restrict__ cursor,
                               int* __restrict__ epack) {
    int e = blockIdx.x * 256 + threadIdx.x;
    if (e < E_N) {
        int d = dst[e];
        int pos = offs[d] + atomicAdd(&cursor[d], 1);
        epack[pos] = src[e] | (etype[e] << 17) | (edir[e] << 26);
    }
}

// ---------------- aggregate: HALF-WAVE (32 lanes) per dst node, bf16 gathers ----------------
// Apre[v][0..255]=dir0 agg, [256..511]=dir1 agg (bf16).
__global__ __launch_bounds__(256)
void aggregate(const unsigned short* __restrict__ xbf,
               const unsigned short* __restrict__ relbf,
               const float* __restrict__ degi,
               const int* __restrict__ cnt, const int* __restrict__ offs,
               const int* __restrict__ epack, unsigned short* __restrict__ Apre) {
    const int node = (blockIdx.x * 256 + threadIdx.x) >> 5;
    const int lane = threadIdx.x & 31;
    if (node >= V_N) return;
    const int v = node;
    const int n = cnt[v];
    const int base = offs[v];
    const float dv = degi[v];
    const int c8 = lane * 8;                 // this lane owns 8 elems of the row

    float a0[8] = {0,0,0,0,0,0,0,0};
    float a1[8] = {0,0,0,0,0,0,0,0};

    int i = 0;
    for (; i + 2 <= n; i += 2) {
        int p0 = epack[base + i];
        int p1 = epack[base + i + 1];
        int s0 = p0 & 0x1FFFF, s1 = p1 & 0x1FFFF;
        int t0 = (p0 >> 17) & 0x1FF, t1 = (p1 >> 17) & 0x1FF;
        float en0 = degi[s0] * dv, en1 = degi[s1] * dv;
        float e00 = (p0 & (1 << 26)) ? 0.f : en0, e01 = en0 - e00;
        float e10 = (p1 & (1 << 26)) ? 0.f : en1, e11 = en1 - e10;
        uint4 xu0 = *(const uint4*)(xbf   + (size_t)s0 * 256 + c8);
        uint4 ru0 = *(const uint4*)(relbf + (size_t)t0 * 256 + c8);
        uint4 xu1 = *(const uint4*)(xbf   + (size_t)s1 * 256 + c8);
        uint4 ru1 = *(const uint4*)(relbf + (size_t)t1 * 256 + c8);
        float m[8];
        m[0] = blo(xu0.x) * blo(ru0.x); m[1] = bhi(xu0.x) * bhi(ru0.x);
        m[2] = blo(xu0.y) * blo(ru0.y); m[3] = bhi(xu0.y) * bhi(ru0.y);
        m[4] = blo(xu0.z) * blo(ru0.z); m[5] = bhi(xu0.z) * bhi(ru0.z);
        m[6] = blo(xu0.w) * blo(ru0.w); m[7] = bhi(xu0.w) * bhi(ru0.w);
        #pragma unroll
        for (int j = 0; j < 8; j++) { a0[j] += m[j] * e00; a1[j] += m[j] * e01; }
        m[0] = blo(xu1.x) * blo(ru1.x); m[1] = bhi(xu1.x) * bhi(ru1.x);
        m[2] = blo(xu1.y) * blo(ru1.y); m[3] = bhi(xu1.y) * bhi(ru1.y);
        m[4] = blo(xu1.z) * blo(ru1.z); m[5] = bhi(xu1.z) * bhi(ru1.z);
        m[6] = blo(xu1.w) * blo(ru1.w); m[7] = bhi(xu1.w) * bhi(ru1.w);
        #pragma unroll
        for (int j = 0; j < 8; j++) { a0[j] += m[j] * e10; a1[j] += m[j] * e11; }
    }
    if (i < n) {
        int p = epack[base + i];
        int s = p & 0x1FFFF;
        int tt = (p >> 17) & 0x1FF;
        float en = degi[s] * dv;
        float e0 = (p & (1 << 26)) ? 0.f : en, e1 = en - e0;
        uint4 xu = *(const uint4*)(xbf   + (size_t)s * 256 + c8);
        uint4 ru = *(const uint4*)(relbf + (size_t)tt * 256 + c8);
        float m[8];
        m[0] = blo(xu.x) * blo(ru.x); m[1] = bhi(xu.x) * bhi(ru.x);
        m[2] = blo(xu.y) * blo(ru.y); m[3] = bhi(xu.y) * bhi(ru.y);
        m[4] = blo(xu.z) * blo(ru.z); m[5] = bhi(xu.z) * bhi(ru.z);
        m[6] = blo(xu.w) * blo(ru.w); m[7] = bhi(xu.w) * bhi(ru.w);
        #pragma unroll
        for (int j = 0; j < 8; j++) { a0[j] += m[j] * e0; a1[j] += m[j] * e1; }
    }

    uint4 u0, u1;
    u0.x = pk2bf(a0[0], a0[1]); u0.y = pk2bf(a0[2], a0[3]);
    u0.z = pk2bf(a0[4], a0[5]); u0.w = pk2bf(a0[6], a0[7]);
    u1.x = pk2bf(a1[0], a1[1]); u1.y = pk2bf(a1[2], a1[3]);
    u1.z = pk2bf(a1[4], a1[5]); u1.w = pk2bf(a1[6], a1[7]);
    *(uint4*)(Apre + (size_t)v * 512 + c8)       = u0;
    *(uint4*)(Apre + (size_t)v * 512 + 256 + c8) = u1;
}

// ---------------- fused GEMM: 256x256 tile, asymmetric pipeline (A 3-deep, B 2-deep) ----------------
// Main loop identical to round-11/12 (proven). Epilogue: 2 phases of 128 rows;
// BN column sums atomically added straight to global `sums` (no partial buffer).
__global__ __launch_bounds__(512)
void mfma_gemm(unsigned short* Ap /* Apre, also h output */,
               const unsigned short* __restrict__ xbf,
               const unsigned short* __restrict__ WcT,
               const float* __restrict__ bias, float* __restrict__ sums) {
    __shared__ __align__(16) unsigned char smem[163840];

    const int t    = threadIdx.x;
    const int m0   = blockIdx.x * 256;
    const int wid  = t >> 6;
    const int lane = t & 63;
    const int wm   = wid >> 1;          // 0..3 row-group
    const int wn   = wid & 1;           // 0..1 col-group
    const int lr   = lane & 15;
    const int qk   = lane >> 4;
    const int sxr  = lr & 7;
    const int wbase = t & 0x1C0;

    int arow[4], acsw[4], brow[4], bcsw[4];
    #pragma unroll
    for (int j = 0; j < 4; ++j) {
        int g = j * 512 + t;
        arow[j] = g >> 3;
        acsw[j] = (g & 7) ^ (arow[j] & 7);
        brow[j] = g >> 3;
        bcsw[j] = (g & 7) ^ (brow[j] & 7);
    }

    auto A_lds = [&](int b3) { return (unsigned short*)(smem + b3 * 32768); };
    auto B_lds = [&](int b2) { return (unsigned short*)(smem + 98304 + b2 * 32768); };

    auto stageA = [&](int buf, int ks) {
        #pragma unroll
        for (int j = 0; j < 4; ++j) {
            int rg = m0 + arow[j];
            if (rg >= V_N) rg = V_N - 1;
            const unsigned short* s = (ks < 8)
                ? Ap  + (size_t)rg * 512 + ks * 64 + acsw[j] * 8
                : xbf + (size_t)rg * 256 + (ks - 8) * 64 + acsw[j] * 8;
            gload16(s, A_lds(buf) + (size_t)(j * 512 + wbase) * 8);
        }
    };
    auto stageB = [&](int buf, int ks) {
        #pragma unroll
        for (int j = 0; j < 4; ++j) {
            const unsigned short* s = WcT + (size_t)brow[j] * 768 + ks * 64 + bcsw[j] * 8;
            gload16(s, B_lds(buf) + (size_t)(j * 512 + wbase) * 8);
        }
    };

    f32x4 acc[4][8];
    #pragma unroll
    for (int m = 0; m < 4; m++)
        #pragma unroll
        for (int n = 0; n < 8; n++)
            acc[m][n] = (f32x4){0.f, 0.f, 0.f, 0.f};

    // prologue: A(0), B(0), A(1)
    stageA(0, 0);
    stageB(0, 0);
    stageA(1, 1);

    #pragma unroll
    for (int ks = 0; ks < 12; ++ks) {
        const int a3 = ks % 3;
        const int b2 = ks & 1;
        if (ks < 11) { asm volatile("s_waitcnt vmcnt(4)" ::: "memory"); }
        else         { asm volatile("s_waitcnt vmcnt(0)" ::: "memory"); }
        __builtin_amdgcn_s_barrier();
        __builtin_amdgcn_sched_barrier(0);
        if (ks + 1 < 12) stageB((ks + 1) & 1, ks + 1);
        if (ks + 2 < 12) stageA((ks + 2) % 3, ks + 2);
        __builtin_amdgcn_sched_barrier(0);
        const unsigned short* Ab = A_lds(a3);
        const unsigned short* Bb = B_lds(b2);
        #pragma unroll
        for (int h = 0; h < 2; ++h) {
            short8 av[4], bv[8];
            #pragma unroll
            for (int m = 0; m < 4; m++)
                av[m] = *(const short8*)&Ab[(size_t)((wm * 64 + m * 16 + lr) * 8 + ((h * 4 + qk) ^ sxr)) * 8];
            #pragma unroll
            for (int n = 0; n < 8; n++)
                bv[n] = *(const short8*)&Bb[(size_t)((wn * 128 + n * 16 + lr) * 8 + ((h * 4 + qk) ^ sxr)) * 8];
            #pragma unroll
            for (int m = 0; m < 4; m++)
                #pragma unroll
                for (int n = 0; n < 8; n++)
                    acc[m][n] = __builtin_amdgcn_mfma_f32_16x16x32_bf16(av[m], bv[n], acc[m][n], 0, 0, 0);
        }
    }
    __syncthreads();

    // ---- epilogue: 2 phases of 128 rows; h = acc/3 + bias (bf16); BN col sums -> global ----
    unsigned short* Cst = (unsigned short*)smem;     // [128][264] ushort = 67584 B
    float* bs = (float*)(smem + 67584);              // 512 floats
    bs[t] = 0.f;
    __syncthreads();

    const float inv3 = 1.f / 3.f;
    float bco[8];
    #pragma unroll
    for (int n = 0; n < 8; n++) bco[n] = bias[wn * 128 + n * 16 + lr];

    float s[8]  = {0.f, 0.f, 0.f, 0.f, 0.f, 0.f, 0.f, 0.f};
    float s2[8] = {0.f, 0.f, 0.f, 0.f, 0.f, 0.f, 0.f, 0.f};

    #pragma unroll
    for (int p = 0; p < 2; ++p) {
        if ((wm >> 1) == p) {
            const int rbase = (wm & 1) * 64;
            #pragma unroll
            for (int m = 0; m < 4; m++) {
                #pragma unroll
                for (int n = 0; n < 8; n++) {
                    const int col = wn * 128 + n * 16 + lr;
                    #pragma unroll
                    for (int j = 0; j < 4; j++) {
                        int rl = rbase + m * 16 + qk * 4 + j;
                        float h = acc[m][n][j] * inv3 + bco[n];
                        if (m0 + p * 128 + rl < V_N) { s[n] += h; s2[n] += h * h; }
                        Cst[rl * 264 + col] = f2bf(h);
                    }
                }
            }
        }
        __syncthreads();
        #pragma unroll
        for (int i = 0; i < 8; ++i) {
            int f = t + i * 512;            // 0..4095 chunks of 8 ushorts
            int row = f >> 5;               // 0..127
            int c8  = (f & 31) * 8;
            int r = m0 + p * 128 + row;
            if (r < V_N) {
                uint4 val = *(const uint4*)&Cst[row * 264 + c8];
                *(uint4*)&Ap[(size_t)r * 512 + c8] = val;
            }
        }
        __syncthreads();
    }

    #pragma unroll
    for (int n = 0; n < 8; n++) {
        s[n]  += __shfl_xor(s[n], 16);  s[n]  += __shfl_xor(s[n], 32);
        s2[n] += __shfl_xor(s2[n], 16); s2[n] += __shfl_xor(s2[n], 32);
    }
    if (lane < 16) {
        #pragma unroll
        for (int n = 0; n < 8; n++) {
            const int col = wn * 128 + n * 16 + lr;
            atomicAdd(&bs[col], s[n]);
            atomicAdd(&bs[256 + col], s2[n]);
        }
    }
    __syncthreads();
    atomicAdd(&sums[t], bs[t]);          // 512 adds/block straight to global
}

// ---------------- fused BN finalize+normalize + rel_out ----------------
// blocks [0,2048): normalize (stride fixed to 2048*256); [2048,2048+119): rel_out.
__global__ __launch_bounds__(256)
void bn_norm2f(const unsigned short* __restrict__ hbf, const float* __restrict__ sums,
               const float* __restrict__ rel_repr, const float* __restrict__ loop_rel,
               const float* __restrict__ w_rel, float* __restrict__ out) {
    const int tt = threadIdx.x;
    if (blockIdx.x < BN_BLKS) {
        __shared__ float msm[256], msr[256];
        {
            float mean = sums[tt] * (1.0f / V_N);
            float var  = sums[256 + tt] * (1.0f / V_N) - mean * mean;
            msm[tt] = mean;
            msr[tt] = rsqrtf(var + BN_EPS);
        }
        __syncthreads();
        const size_t total8 = (size_t)V_N * 32;
        const size_t stride = (size_t)BN_BLKS * 256;
        for (size_t idx = (size_t)blockIdx.x * 256 + tt; idx < total8; idx += stride) {
            size_t v  = idx >> 5;
            int   c8  = (int)(idx & 31) * 8;
            uint4 uv = *(const uint4*)&hbf[v * 512 + c8];
            unsigned int w0 = uv.x, w1 = uv.y, w2 = uv.z, w3 = uv.w;
            float4 h0, h1;
            h0.x = (blo(w0) - msm[c8 + 0]) * msr[c8 + 0];
            h0.y = (bhi(w0) - msm[c8 + 1]) * msr[c8 + 1];
            h0.z = (blo(w1) - msm[c8 + 2]) * msr[c8 + 2];
            h0.w = (bhi(w1) - msm[c8 + 3]) * msr[c8 + 3];
            h1.x = (blo(w2) - msm[c8 + 4]) * msr[c8 + 4];
            h1.y = (bhi(w2) - msm[c8 + 5]) * msr[c8 + 5];
            h1.z = (blo(w3) - msm[c8 + 6]) * msr[c8 + 6];
            h1.w = (bhi(w3) - msm[c8 + 7]) * msr[c8 + 7];
            float* o = out + v * 256 + c8;
            *(float4*)o       = h0;
            *(float4*)(o + 4) = h1;
        }
    } else {
        const int g = tt >> 6;              // 4 rows per block
        const int l = tt & 63;
        const int r = (blockIdx.x - BN_BLKS) * 4 + g;
        if (r <= NREL2) {
            const float* row = (r < NREL2) ? (rel_repr + (size_t)r * IN_C) : loop_rel;
            float s = 0.f;
            #pragma unroll
            for (int q = 0; q < 4; q++) {
                int k = l + q * 64;
                s += row[k] * w_rel[(size_t)k * OUT_C + (OUT_C - 1)];
            }
            #pragma unroll
            for (int m = 32; m >= 1; m >>= 1) s += __shfl_xor(s, m);
            if (l == 0) out[(size_t)V_N * OUT_C + r] = s;
        }
    }
}

// ---------------- launch ----------------

extern "C" void kernel_launch(void* const* d_in, const int* in_sizes, int n_in,
                              void* d_out, int out_size, void* d_ws, size_t ws_size,
                              hipStream_t stream) {
    const float* x        = (const float*)d_in[0];
    const float* rel_repr = (const float*)d_in[1];
    const float* w        = (const float*)d_in[2];
    const float* w_rel    = (const float*)d_in[3];
    const float* loop_rel = (const float*)d_in[4];
    const float* bias     = (const float*)d_in[5];
    const int*   src      = (const int*)d_in[6];
    const int*   dst      = (const int*)d_in[7];
    const int*   etype    = (const int*)d_in[8];
    const int*   edir     = (const int*)d_in[9];
    float* out = (float*)d_out;
    unsigned short* xbf   = (unsigned short*)d_out;                      // [V][256] bf16
    unsigned short* relbf = (unsigned short*)((char*)d_out + 51200000);  // [NREL2][256] bf16
    // both dead before bn_norm2f overwrites d_out with f32 output

    // workspace layout (105.60 MB, within round-2-proven bound)
    char* wsb = (char*)d_ws;
    int*   cnt     = (int*)(wsb + 0);              // 400,000
    int*   cursor  = (int*)(wsb + 400000);         // 400,000
    int*   offs    = (int*)(wsb + 800000);         // 400,000
    float* degi    = (float*)(wsb + 1200000);      // 400,000
    int*   bsum    = (int*)(wsb + 1600000);        // 392
    int*   epack   = (int*)(wsb + 1601792);        // 1,200,000
    float* sums    = (float*)(wsb + 2803840);      // 2048
    unsigned short* WcT  = (unsigned short*)(wsb + 2805888);   // 393,216
    unsigned short* Apre = (unsigned short*)(wsb + 3199104);   // 102,400,000

    hipMemsetAsync(wsb, 0, 800000, stream);        // cnt + cursor
    hipMemsetAsync(sums, 0, 2048, stream);

    count_convx<<<CNT_BLKS + CVX_BLKS, 256, 0, stream>>>(dst, cnt, x, xbf);
    scan1_conv<<<NB_SCAN + 192 + 15, 1024, 0, stream>>>(cnt, bsum, degi,
                                                        w, loop_rel, WcT,
                                                        rel_repr, relbf);
    scan3b<<<NB_SCAN, 1024, 0, stream>>>(cnt, bsum, offs);
    scatter_kernel<<<CNT_BLKS, 256, 0, stream>>>(dst, src, etype, edir,
                                                 offs, cursor, epack);
    aggregate<<<(V_N * 32 + 255) / 256, 256, 0, stream>>>(xbf, relbf, degi, cnt, offs,
                                                          epack, Apre);
    mfma_gemm<<<MTILES, 512, 0, stream>>>(Apre, xbf, WcT, bias, sums);
    bn_norm2f<<<BN_BLKS + REL_BLKS, 256, 0, stream>>>(Apre, sums, rel_repr, loop_rel,
                                                      w_rel, out);
}